// Round 1
// baseline (947.895 us; speedup 1.0000x reference)
//
#include <hip/hip_runtime.h>

#define NPIX 9216
#define CIN 72
#define CP 96

typedef __attribute__((ext_vector_type(8))) short bf16x8;
typedef __attribute__((ext_vector_type(4))) float f32x4;

#define MFMA16(A,B,C) __builtin_amdgcn_mfma_f32_16x16x32_bf16(A,B,C,0,0,0)

static __device__ __forceinline__ unsigned short f2bf(float f) {
  unsigned u = __float_as_uint(f);
  u += 0x7fffu + ((u >> 16) & 1u);
  return (unsigned short)(u >> 16);
}
static __device__ __forceinline__ float bf2f(unsigned short h) {
  return __uint_as_float(((unsigned)h) << 16);
}

// ---------------------------------------------------------------------------
// Kernel 1: QKV projection (fp32 math), emit:
//   QHI/QLO/KHI/KLO : bf16 [B][NPIX][96]  (c-fast, cols 72..95 zero)
//   VG              : bf16 [B][80][NPIX]  (rows 72..79 zero)
// ---------------------------------------------------------------------------
__global__ __launch_bounds__(256) void qkv_kernel(
    const float* __restrict__ x,
    const float* __restrict__ Wq, const float* __restrict__ bq,
    const float* __restrict__ Wk, const float* __restrict__ bk,
    const float* __restrict__ Wv, const float* __restrict__ bv,
    unsigned short* __restrict__ QHI, unsigned short* __restrict__ QLO,
    unsigned short* __restrict__ KHI, unsigned short* __restrict__ KLO,
    unsigned short* __restrict__ VG)
{
  __shared__ float xs[CIN * 32];
  const int t  = threadIdx.x;
  const int b  = blockIdx.y;
  const int n0 = blockIdx.x * 32;
  const int nl = t & 31;
  const int dg = t >> 5;          // 0..7, each handles 9 output channels
  const int d0 = dg * 9;

  for (int e = t; e < CIN * 32; e += 256) {
    int c = e >> 5, j = e & 31;
    xs[e] = x[((size_t)b * CIN + c) * NPIX + n0 + j];
  }
  __syncthreads();

  float aq[9], ak[9], av[9];
#pragma unroll
  for (int dd = 0; dd < 9; ++dd) { aq[dd] = bq[d0+dd]; ak[dd] = bk[d0+dd]; av[dd] = bv[d0+dd]; }

  for (int c = 0; c < CIN; ++c) {
    float xv = xs[c * 32 + nl];
#pragma unroll
    for (int dd = 0; dd < 9; ++dd) {
      aq[dd] += Wq[(d0+dd) * CIN + c] * xv;
      ak[dd] += Wk[(d0+dd) * CIN + c] * xv;
      av[dd] += Wv[(d0+dd) * CIN + c] * xv;
    }
  }

  const int n = n0 + nl;
  const size_t rowbase = ((size_t)b * NPIX + n) * CP;
#pragma unroll
  for (int dd = 0; dd < 9; ++dd) {
    int d = d0 + dd;
    unsigned short qh = f2bf(aq[dd]);
    unsigned short ql = f2bf(aq[dd] - bf2f(qh));
    unsigned short kh = f2bf(ak[dd]);
    unsigned short kl = f2bf(ak[dd] - bf2f(kh));
    QHI[rowbase + d] = qh;  QLO[rowbase + d] = ql;
    KHI[rowbase + d] = kh;  KLO[rowbase + d] = kl;
    VG[((size_t)b * 80 + d) * NPIX + n] = f2bf(av[dd]);
  }
  // zero pads
  if (t < 32) {
    const size_t pb = ((size_t)b * NPIX + n0 + t) * CP;
    for (int c = CIN; c < CP; ++c) { QHI[pb+c]=0; QLO[pb+c]=0; KHI[pb+c]=0; KLO[pb+c]=0; }
    for (int cp = 0; cp < 8; ++cp) VG[((size_t)b * 80 + 72 + cp) * NPIX + n0 + t] = 0;
  }
}

// ---------------------------------------------------------------------------
// Kernel 2: fused flash attention. 144 blocks = 72 i-tiles(128 rows) x B.
// 4 waves/block, each wave owns 32 rows (2 m-tiles). BJ=64 per iteration.
// Scores in split-bf16 (qhi*khi + qlo*khi + qhi*klo), fp32 accum.
// Output WVG: fp32 [B][NPIX][72]  (wv transposed: [pixel][channel])
// ---------------------------------------------------------------------------
#define KSP 104   // LDS row stride for k tiles (ushorts)
#define VSP 72    // LDS row stride for v tile
#define PSP 72    // LDS row stride for p tile

__global__ __launch_bounds__(256) void flash_kernel(
    const unsigned short* __restrict__ QHI, const unsigned short* __restrict__ QLO,
    const unsigned short* __restrict__ KHI, const unsigned short* __restrict__ KLO,
    const unsigned short* __restrict__ VG, float* __restrict__ WVG)
{
  __shared__ __align__(16) unsigned short ls_kh[64 * KSP];
  __shared__ __align__(16) unsigned short ls_kl[64 * KSP];
  __shared__ __align__(16) unsigned short ls_vs[80 * VSP];
  __shared__ __align__(16) unsigned short ls_ps[4][32 * PSP];

  const int t    = threadIdx.x;
  const int w    = t >> 6;
  const int lane = t & 63;
  const int quad = lane >> 4;
  const int l15  = lane & 15;
  const int b    = blockIdx.y;
  const int i0w  = blockIdx.x * 128 + w * 32;

  // Q fragments in registers for the whole block (A-operand layout:
  // m = lane&15, k = quad*8 + j  -> 16B contiguous in [row][c] storage)
  bf16x8 qh[2][3], ql[2][3];
#pragma unroll
  for (int mi = 0; mi < 2; ++mi)
#pragma unroll
    for (int ks = 0; ks < 3; ++ks) {
      size_t off = ((size_t)b * NPIX + i0w + mi * 16 + l15) * CP + ks * 32 + quad * 8;
      qh[mi][ks] = *(const bf16x8*)(QHI + off);
      ql[mi][ks] = *(const bf16x8*)(QLO + off);
    }

  f32x4 oacc[2][5];
#pragma unroll
  for (int mi = 0; mi < 2; ++mi)
#pragma unroll
    for (int nt = 0; nt < 5; ++nt) oacc[mi][nt] = (f32x4){0.f, 0.f, 0.f, 0.f};
  float m_run[2][4], l_run[2][4];
#pragma unroll
  for (int mi = 0; mi < 2; ++mi)
#pragma unroll
    for (int r = 0; r < 4; ++r) { m_run[mi][r] = -1e30f; l_run[mi][r] = 0.f; }

  for (int jt = 0; jt < NPIX / 64; ++jt) {
    const int j0 = jt * 64;
    // ---- stage K(hi,lo) and V tiles into LDS ----
    {
      const unsigned short* kh = KHI + ((size_t)b * NPIX + j0) * CP;
      const unsigned short* kl = KLO + ((size_t)b * NPIX + j0) * CP;
      for (int idx = t; idx < 768; idx += 256) {
        int r = idx / 12, c = idx % 12;
        *(uint4*)(ls_kh + r * KSP + c * 8) = *(const uint4*)(kh + r * CP + c * 8);
        *(uint4*)(ls_kl + r * KSP + c * 8) = *(const uint4*)(kl + r * CP + c * 8);
      }
      for (int idx = t; idx < 640; idx += 256) {
        int r = idx >> 3, c = idx & 7;
        *(uint4*)(ls_vs + r * VSP + c * 8) =
            *(const uint4*)(VG + ((size_t)b * 80 + r) * NPIX + j0 + c * 8);
      }
    }
    __syncthreads();

    // ---- scores: S = Qhi*Khi + Qlo*Khi + Qhi*Klo ----
    f32x4 sacc[2][4];
#pragma unroll
    for (int mi = 0; mi < 2; ++mi)
#pragma unroll
      for (int ni = 0; ni < 4; ++ni) sacc[mi][ni] = (f32x4){0.f, 0.f, 0.f, 0.f};

#pragma unroll
    for (int ni = 0; ni < 4; ++ni) {
      const unsigned short* krh = ls_kh + (ni * 16 + l15) * KSP;
      const unsigned short* krl = ls_kl + (ni * 16 + l15) * KSP;
#pragma unroll
      for (int ks = 0; ks < 3; ++ks) {
        bf16x8 fkh = *(const bf16x8*)(krh + ks * 32 + quad * 8);
        bf16x8 fkl = *(const bf16x8*)(krl + ks * 32 + quad * 8);
#pragma unroll
        for (int mi = 0; mi < 2; ++mi) {
          sacc[mi][ni] = MFMA16(qh[mi][ks], fkh, sacc[mi][ni]);
          sacc[mi][ni] = MFMA16(ql[mi][ks], fkh, sacc[mi][ni]);
          sacc[mi][ni] = MFMA16(qh[mi][ks], fkl, sacc[mi][ni]);
        }
      }
    }

    // ---- online softmax (wave-local; D layout: col=lane&15, row=quad*4+reg) ----
    unsigned short* psw = ls_ps[w];
#pragma unroll
    for (int mi = 0; mi < 2; ++mi) {
      float al[4];
#pragma unroll
      for (int r = 0; r < 4; ++r) {
        float tm = fmaxf(fmaxf(sacc[mi][0][r], sacc[mi][1][r]),
                         fmaxf(sacc[mi][2][r], sacc[mi][3][r]));
        tm = fmaxf(tm, __shfl_xor(tm, 1));
        tm = fmaxf(tm, __shfl_xor(tm, 2));
        tm = fmaxf(tm, __shfl_xor(tm, 4));
        tm = fmaxf(tm, __shfl_xor(tm, 8));
        float mold = m_run[mi][r];
        float mnew = fmaxf(mold, tm);
        float alpha = __expf(mold - mnew);
        float rs = 0.f;
#pragma unroll
        for (int ni = 0; ni < 4; ++ni) {
          float pv = __expf(sacc[mi][ni][r] - mnew);
          sacc[mi][ni][r] = pv;
          rs += pv;
        }
        rs += __shfl_xor(rs, 1);
        rs += __shfl_xor(rs, 2);
        rs += __shfl_xor(rs, 4);
        rs += __shfl_xor(rs, 8);
        m_run[mi][r] = mnew;
        l_run[mi][r] = l_run[mi][r] * alpha + rs;
        al[r] = alpha;
      }
#pragma unroll
      for (int nt = 0; nt < 5; ++nt)
#pragma unroll
        for (int r = 0; r < 4; ++r) oacc[mi][nt][r] *= al[r];
      // write P (bf16) to LDS in [row][j] layout for the A-operand of PV
#pragma unroll
      for (int ni = 0; ni < 4; ++ni)
#pragma unroll
        for (int r = 0; r < 4; ++r) {
          int row = mi * 16 + quad * 4 + r;
          int col = ni * 16 + l15;
          psw[row * PSP + col] = f2bf(sacc[mi][ni][r]);
        }
    }
    __syncthreads();

    // ---- PV: O[i][c] += P[i][j] * V[c][j] ----
#pragma unroll
    for (int js = 0; js < 2; ++js) {
      bf16x8 pf[2];
#pragma unroll
      for (int mi = 0; mi < 2; ++mi)
        pf[mi] = *(const bf16x8*)(psw + (mi * 16 + l15) * PSP + js * 32 + quad * 8);
#pragma unroll
      for (int nt = 0; nt < 5; ++nt) {
        bf16x8 vf = *(const bf16x8*)(ls_vs + (nt * 16 + l15) * VSP + js * 32 + quad * 8);
#pragma unroll
        for (int mi = 0; mi < 2; ++mi)
          oacc[mi][nt] = MFMA16(pf[mi], vf, oacc[mi][nt]);
      }
    }
    __syncthreads();
  }

  // ---- epilogue: wv = O / l, store [pixel][channel] fp32 ----
#pragma unroll
  for (int mi = 0; mi < 2; ++mi)
#pragma unroll
    for (int r = 0; r < 4; ++r) {
      float inv = 1.0f / l_run[mi][r];
      int row = i0w + mi * 16 + quad * 4 + r;
      float* dst = WVG + ((size_t)b * NPIX + row) * 72;
#pragma unroll
      for (int nt = 0; nt < 5; ++nt) {
        int col = nt * 16 + l15;
        if (col < 72) dst[col] = oacc[mi][nt][r] * inv;
      }
    }
}

// ---------------------------------------------------------------------------
// Kernel 3: factor-4 pooling: out[b][g][n] = sum_f x[b][4g+f][n]*wv[b][4g+f][n]
// ---------------------------------------------------------------------------
__global__ __launch_bounds__(256) void pool_kernel(
    const float* __restrict__ x, const float* __restrict__ WVG,
    float* __restrict__ out)
{
  int id = blockIdx.x * 256 + threadIdx.x;
  if (id >= 2 * 18 * NPIX) return;
  int n = id % NPIX;
  int rest = id / NPIX;
  int g = rest % 18, b = rest / 18;
  float4 wv4 = *(const float4*)(WVG + ((size_t)b * NPIX + n) * 72 + g * 4);
  const float* xp = x + ((size_t)b * CIN + g * 4) * NPIX + n;
  float s = xp[0] * wv4.x + xp[NPIX] * wv4.y + xp[2 * NPIX] * wv4.z + xp[3 * NPIX] * wv4.w;
  out[id] = s;
}

// ---------------------------------------------------------------------------
extern "C" void kernel_launch(void* const* d_in, const int* in_sizes, int n_in,
                              void* d_out, int out_size, void* d_ws, size_t ws_size,
                              hipStream_t stream) {
  const float* x  = (const float*)d_in[0];
  const float* Wq = (const float*)d_in[1];
  const float* bq = (const float*)d_in[2];
  const float* Wk = (const float*)d_in[3];
  const float* bk = (const float*)d_in[4];
  const float* Wv = (const float*)d_in[5];
  const float* bv = (const float*)d_in[6];
  float* out = (float*)d_out;

  char* p = (char*)d_ws;
  const size_t szQK = (size_t)2 * NPIX * CP * 2;     // 3,538,944 B each
  unsigned short* QHI = (unsigned short*)p; p += szQK;
  unsigned short* QLO = (unsigned short*)p; p += szQK;
  unsigned short* KHI = (unsigned short*)p; p += szQK;
  unsigned short* KLO = (unsigned short*)p; p += szQK;
  unsigned short* VG  = (unsigned short*)p; p += (size_t)2 * 80 * NPIX * 2;
  float* WVG = (float*)p;                            // 5,308,416 B
  // total ws use ~22.4 MB

  qkv_kernel<<<dim3(NPIX / 32, 2), 256, 0, stream>>>(x, Wq, bq, Wk, bk, Wv, bv,
                                                     QHI, QLO, KHI, KLO, VG);
  flash_kernel<<<dim3(NPIX / 128, 2), 256, 0, stream>>>(QHI, QLO, KHI, KLO, VG, WVG);
  pool_kernel<<<(2 * 18 * NPIX + 255) / 256, 256, 0, stream>>>(x, WVG, out);
}

// Round 2
// 609.635 us; speedup vs baseline: 1.5549x; 1.5549x over previous
//
#include <hip/hip_runtime.h>

#define NPIX 9216
#define CIN 72
#define CP 96
#define SPLITS 8
#define JCHUNK (NPIX / SPLITS)   // 1152
#define JTILES (JCHUNK / 64)     // 18

typedef __attribute__((ext_vector_type(8))) short bf16x8;
typedef __attribute__((ext_vector_type(4))) float f32x4;

#define MFMA16(A,B,C) __builtin_amdgcn_mfma_f32_16x16x32_bf16(A,B,C,0,0,0)

static __device__ __forceinline__ unsigned short f2bf(float f) {
  unsigned u = __float_as_uint(f);
  u += 0x7fffu + ((u >> 16) & 1u);
  return (unsigned short)(u >> 16);
}
static __device__ __forceinline__ float bf2f(unsigned short h) {
  return __uint_as_float(((unsigned)h) << 16);
}

// ---------------------------------------------------------------------------
// Kernel 1: QKV projection (fp32 math), emit:
//   QHI/QLO/KHI/KLO : bf16 [B][NPIX][96]  (c-fast, cols 72..95 zero)
//   VG              : bf16 [B][80][NPIX]  (rows 72..79 zero)
// ---------------------------------------------------------------------------
__global__ __launch_bounds__(256) void qkv_kernel(
    const float* __restrict__ x,
    const float* __restrict__ Wq, const float* __restrict__ bq,
    const float* __restrict__ Wk, const float* __restrict__ bk,
    const float* __restrict__ Wv, const float* __restrict__ bv,
    unsigned short* __restrict__ QHI, unsigned short* __restrict__ QLO,
    unsigned short* __restrict__ KHI, unsigned short* __restrict__ KLO,
    unsigned short* __restrict__ VG)
{
  __shared__ float xs[CIN * 32];
  const int t  = threadIdx.x;
  const int b  = blockIdx.y;
  const int n0 = blockIdx.x * 32;
  const int nl = t & 31;
  const int dg = t >> 5;          // 0..7, each handles 9 output channels
  const int d0 = dg * 9;

  for (int e = t; e < CIN * 32; e += 256) {
    int c = e >> 5, j = e & 31;
    xs[e] = x[((size_t)b * CIN + c) * NPIX + n0 + j];
  }
  __syncthreads();

  float aq[9], ak[9], av[9];
#pragma unroll
  for (int dd = 0; dd < 9; ++dd) { aq[dd] = bq[d0+dd]; ak[dd] = bk[d0+dd]; av[dd] = bv[d0+dd]; }

  for (int c = 0; c < CIN; ++c) {
    float xv = xs[c * 32 + nl];
#pragma unroll
    for (int dd = 0; dd < 9; ++dd) {
      aq[dd] += Wq[(d0+dd) * CIN + c] * xv;
      ak[dd] += Wk[(d0+dd) * CIN + c] * xv;
      av[dd] += Wv[(d0+dd) * CIN + c] * xv;
    }
  }

  const int n = n0 + nl;
  const size_t rowbase = ((size_t)b * NPIX + n) * CP;
#pragma unroll
  for (int dd = 0; dd < 9; ++dd) {
    int d = d0 + dd;
    unsigned short qh = f2bf(aq[dd]);
    unsigned short ql = f2bf(aq[dd] - bf2f(qh));
    unsigned short kh = f2bf(ak[dd]);
    unsigned short kl = f2bf(ak[dd] - bf2f(kh));
    QHI[rowbase + d] = qh;  QLO[rowbase + d] = ql;
    KHI[rowbase + d] = kh;  KLO[rowbase + d] = kl;
    VG[((size_t)b * 80 + d) * NPIX + n] = f2bf(av[dd]);
  }
  // zero pads
  if (t < 32) {
    const size_t pb = ((size_t)b * NPIX + n0 + t) * CP;
    for (int c = CIN; c < CP; ++c) { QHI[pb+c]=0; QLO[pb+c]=0; KHI[pb+c]=0; KLO[pb+c]=0; }
    for (int cp = 0; cp < 8; ++cp) VG[((size_t)b * 80 + 72 + cp) * NPIX + n0 + t] = 0;
  }
}

// ---------------------------------------------------------------------------
// Kernel 2: fused flash attention with split-j.
// Grid: (72 i-tiles, B, SPLITS). Each block: 128 rows x (NPIX/SPLITS) j's.
// 4 waves/block, each wave owns 32 rows (2 m-tiles). BJ=64 per iteration.
// LDS: K tiles aliased with P tiles (union) -> 38.1 KB -> 4 blocks/CU.
// Scores in split-bf16 (qhi*khi + qlo*khi + qhi*klo), fp32 accum.
// Output: OPART fp32 [S][B][NPIX][72] unnormalized, MLPART float2 [S][B][NPIX]
// ---------------------------------------------------------------------------
#define KSP 104   // LDS row stride for k tiles (ushorts)
#define VSP 72    // LDS row stride for v tile
#define PSP 72    // LDS row stride for p tile

__global__ __launch_bounds__(256, 4) void flash_kernel(
    const unsigned short* __restrict__ QHI, const unsigned short* __restrict__ QLO,
    const unsigned short* __restrict__ KHI, const unsigned short* __restrict__ KLO,
    const unsigned short* __restrict__ VG,
    float* __restrict__ OPART, float2* __restrict__ MLPART)
{
  // K tiles (live: stage->scores) aliased with P tiles (live: softmax->PV)
  __shared__ __align__(16) union {
    struct { unsigned short kh[64 * KSP]; unsigned short kl[64 * KSP]; } k;
    unsigned short ps[4][32 * PSP];
  } u;
  __shared__ __align__(16) unsigned short ls_vs[80 * VSP];

  const int t    = threadIdx.x;
  const int w    = t >> 6;
  const int lane = t & 63;
  const int quad = lane >> 4;
  const int l15  = lane & 15;
  const int b    = blockIdx.y;
  const int sp   = blockIdx.z;
  const int i0w  = blockIdx.x * 128 + w * 32;

  // Q fragments in registers for the whole block (A-operand layout:
  // m = lane&15, k = quad*8 + j  -> 16B contiguous in [row][c] storage)
  bf16x8 qh[2][3], ql[2][3];
#pragma unroll
  for (int mi = 0; mi < 2; ++mi)
#pragma unroll
    for (int ks = 0; ks < 3; ++ks) {
      size_t off = ((size_t)b * NPIX + i0w + mi * 16 + l15) * CP + ks * 32 + quad * 8;
      qh[mi][ks] = *(const bf16x8*)(QHI + off);
      ql[mi][ks] = *(const bf16x8*)(QLO + off);
    }

  f32x4 oacc[2][5];
#pragma unroll
  for (int mi = 0; mi < 2; ++mi)
#pragma unroll
    for (int nt = 0; nt < 5; ++nt) oacc[mi][nt] = (f32x4){0.f, 0.f, 0.f, 0.f};
  float m_run[2][4], l_run[2][4];
#pragma unroll
  for (int mi = 0; mi < 2; ++mi)
#pragma unroll
    for (int r = 0; r < 4; ++r) { m_run[mi][r] = -1e30f; l_run[mi][r] = 0.f; }

  for (int jt = 0; jt < JTILES; ++jt) {
    const int j0 = sp * JCHUNK + jt * 64;
    // ---- stage K(hi,lo) and V tiles into LDS ----
    {
      const unsigned short* kh = KHI + ((size_t)b * NPIX + j0) * CP;
      const unsigned short* kl = KLO + ((size_t)b * NPIX + j0) * CP;
      for (int idx = t; idx < 768; idx += 256) {
        int r = idx / 12, c = idx % 12;
        *(uint4*)(u.k.kh + r * KSP + c * 8) = *(const uint4*)(kh + r * CP + c * 8);
        *(uint4*)(u.k.kl + r * KSP + c * 8) = *(const uint4*)(kl + r * CP + c * 8);
      }
      for (int idx = t; idx < 640; idx += 256) {
        int r = idx >> 3, c = idx & 7;
        *(uint4*)(ls_vs + r * VSP + c * 8) =
            *(const uint4*)(VG + ((size_t)b * 80 + r) * NPIX + j0 + c * 8);
      }
    }
    __syncthreads();

    // ---- scores: S = Qhi*Khi + Qlo*Khi + Qhi*Klo ----
    f32x4 sacc[2][4];
#pragma unroll
    for (int mi = 0; mi < 2; ++mi)
#pragma unroll
      for (int ni = 0; ni < 4; ++ni) sacc[mi][ni] = (f32x4){0.f, 0.f, 0.f, 0.f};

#pragma unroll
    for (int ni = 0; ni < 4; ++ni) {
      const unsigned short* krh = u.k.kh + (ni * 16 + l15) * KSP;
      const unsigned short* krl = u.k.kl + (ni * 16 + l15) * KSP;
#pragma unroll
      for (int ks = 0; ks < 3; ++ks) {
        bf16x8 fkh = *(const bf16x8*)(krh + ks * 32 + quad * 8);
        bf16x8 fkl = *(const bf16x8*)(krl + ks * 32 + quad * 8);
#pragma unroll
        for (int mi = 0; mi < 2; ++mi) {
          sacc[mi][ni] = MFMA16(qh[mi][ks], fkh, sacc[mi][ni]);
          sacc[mi][ni] = MFMA16(ql[mi][ks], fkh, sacc[mi][ni]);
          sacc[mi][ni] = MFMA16(qh[mi][ks], fkl, sacc[mi][ni]);
        }
      }
    }
    __syncthreads();   // K tiles dead after this -> P may overwrite them

    // ---- online softmax (wave-local; D layout: col=lane&15, row=quad*4+reg) ----
    unsigned short* psw = u.ps[w];
#pragma unroll
    for (int mi = 0; mi < 2; ++mi) {
      float al[4];
#pragma unroll
      for (int r = 0; r < 4; ++r) {
        float tm = fmaxf(fmaxf(sacc[mi][0][r], sacc[mi][1][r]),
                         fmaxf(sacc[mi][2][r], sacc[mi][3][r]));
        tm = fmaxf(tm, __shfl_xor(tm, 1));
        tm = fmaxf(tm, __shfl_xor(tm, 2));
        tm = fmaxf(tm, __shfl_xor(tm, 4));
        tm = fmaxf(tm, __shfl_xor(tm, 8));
        float mold = m_run[mi][r];
        float mnew = fmaxf(mold, tm);
        float alpha = __expf(mold - mnew);
        float rs = 0.f;
#pragma unroll
        for (int ni = 0; ni < 4; ++ni) {
          float pv = __expf(sacc[mi][ni][r] - mnew);
          sacc[mi][ni][r] = pv;
          rs += pv;
        }
        rs += __shfl_xor(rs, 1);
        rs += __shfl_xor(rs, 2);
        rs += __shfl_xor(rs, 4);
        rs += __shfl_xor(rs, 8);
        m_run[mi][r] = mnew;
        l_run[mi][r] = l_run[mi][r] * alpha + rs;
        al[r] = alpha;
      }
#pragma unroll
      for (int nt = 0; nt < 5; ++nt)
#pragma unroll
        for (int r = 0; r < 4; ++r) oacc[mi][nt][r] *= al[r];
      // write P (bf16) to LDS in [row][j] layout for the A-operand of PV
      // (per-wave private region; no cross-wave hazard)
#pragma unroll
      for (int ni = 0; ni < 4; ++ni)
#pragma unroll
        for (int r = 0; r < 4; ++r) {
          int row = mi * 16 + quad * 4 + r;
          int col = ni * 16 + l15;
          psw[row * PSP + col] = f2bf(sacc[mi][ni][r]);
        }
    }

    // ---- PV: O[i][c] += P[i][j] * V[c][j]  (own-wave P + shared read-only V) ----
#pragma unroll
    for (int js = 0; js < 2; ++js) {
      bf16x8 pf[2];
#pragma unroll
      for (int mi = 0; mi < 2; ++mi)
        pf[mi] = *(const bf16x8*)(psw + (mi * 16 + l15) * PSP + js * 32 + quad * 8);
#pragma unroll
      for (int nt = 0; nt < 5; ++nt) {
        bf16x8 vf = *(const bf16x8*)(ls_vs + (nt * 16 + l15) * VSP + js * 32 + quad * 8);
#pragma unroll
        for (int mi = 0; mi < 2; ++mi)
          oacc[mi][nt] = MFMA16(pf[mi], vf, oacc[mi][nt]);
      }
    }
    __syncthreads();   // all PV reads done before next stage overwrites
  }

  // ---- epilogue: store unnormalized partial O + (m,l) per row ----
  const size_t sb = (size_t)(sp * 2 + b);
#pragma unroll
  for (int mi = 0; mi < 2; ++mi)
#pragma unroll
    for (int r = 0; r < 4; ++r) {
      int row = i0w + mi * 16 + quad * 4 + r;
      float* dst = OPART + (sb * NPIX + row) * 72;
#pragma unroll
      for (int nt = 0; nt < 5; ++nt) {
        int col = nt * 16 + l15;
        if (col < 72) dst[col] = oacc[mi][nt][r];
      }
      if (l15 == 0)
        MLPART[sb * NPIX + row] = make_float2(m_run[mi][r], l_run[mi][r]);
    }
}

// ---------------------------------------------------------------------------
// Kernel 3: combine splits + factor-4 pooling, fused.
// out[b][g][n] = sum_f x[b][4g+f][n] * wv[b][4g+f][n]
// wv[.][c][n] = (sum_s OPART[s][b][n][c] * e_s) / (sum_s l_s * e_s), e_s=exp(m_s-M)
// ---------------------------------------------------------------------------
__global__ __launch_bounds__(256) void combine_pool_kernel(
    const float* __restrict__ x, const float* __restrict__ OPART,
    const float2* __restrict__ MLPART, float* __restrict__ out)
{
  int id = blockIdx.x * 256 + threadIdx.x;
  if (id >= 2 * 18 * NPIX) return;
  int n = id % NPIX;
  int rest = id / NPIX;
  int g = rest % 18, b = rest / 18;

  float ms[SPLITS], ls[SPLITS];
  float M = -1e30f;
#pragma unroll
  for (int s = 0; s < SPLITS; ++s) {
    float2 ml = MLPART[((size_t)(s * 2 + b)) * NPIX + n];
    ms[s] = ml.x; ls[s] = ml.y;
    M = fmaxf(M, ml.x);
  }
  float L = 0.f;
  float4 acc = make_float4(0.f, 0.f, 0.f, 0.f);
#pragma unroll
  for (int s = 0; s < SPLITS; ++s) {
    float e = __expf(ms[s] - M);
    L += ls[s] * e;
    float4 o = *(const float4*)(OPART + (((size_t)(s * 2 + b)) * NPIX + n) * 72 + g * 4);
    acc.x += o.x * e; acc.y += o.y * e; acc.z += o.z * e; acc.w += o.w * e;
  }
  float inv = 1.0f / L;
  const float* xp = x + ((size_t)b * CIN + g * 4) * NPIX + n;
  float s = xp[0] * acc.x * inv + xp[NPIX] * acc.y * inv +
            xp[2 * NPIX] * acc.z * inv + xp[3 * NPIX] * acc.w * inv;
  out[id] = s;
}

// ---------------------------------------------------------------------------
extern "C" void kernel_launch(void* const* d_in, const int* in_sizes, int n_in,
                              void* d_out, int out_size, void* d_ws, size_t ws_size,
                              hipStream_t stream) {
  const float* x  = (const float*)d_in[0];
  const float* Wq = (const float*)d_in[1];
  const float* bq = (const float*)d_in[2];
  const float* Wk = (const float*)d_in[3];
  const float* bk = (const float*)d_in[4];
  const float* Wv = (const float*)d_in[5];
  const float* bv = (const float*)d_in[6];
  float* out = (float*)d_out;

  char* p = (char*)d_ws;
  const size_t szQK = (size_t)2 * NPIX * CP * 2;     // 3,538,944 B each
  unsigned short* QHI = (unsigned short*)p; p += szQK;
  unsigned short* QLO = (unsigned short*)p; p += szQK;
  unsigned short* KHI = (unsigned short*)p; p += szQK;
  unsigned short* KLO = (unsigned short*)p; p += szQK;
  unsigned short* VG  = (unsigned short*)p; p += (size_t)2 * 80 * NPIX * 2;
  float* OPART = (float*)p; p += (size_t)SPLITS * 2 * NPIX * 72 * 4;  // 42.5 MB
  float2* MLPART = (float2*)p; p += (size_t)SPLITS * 2 * NPIX * 8;    // 1.2 MB
  // total ws use ~61 MB

  qkv_kernel<<<dim3(NPIX / 32, 2), 256, 0, stream>>>(x, Wq, bq, Wk, bk, Wv, bv,
                                                     QHI, QLO, KHI, KLO, VG);
  flash_kernel<<<dim3(NPIX / 128, 2, SPLITS), 256, 0, stream>>>(QHI, QLO, KHI, KLO, VG,
                                                                OPART, MLPART);
  combine_pool_kernel<<<(2 * 18 * NPIX + 255) / 256, 256, 0, stream>>>(x, OPART, MLPART, out);
}

// Round 3
// 339.913 us; speedup vs baseline: 2.7886x; 1.7935x over previous
//
#include <hip/hip_runtime.h>

#define NPIX 9216
#define CIN 72
#define CP 96
#define SPLITS 8
#define JCHUNK (NPIX / SPLITS)   // 1152
#define JTILES (JCHUNK / 64)     // 18

typedef __attribute__((ext_vector_type(8))) short bf16x8;
typedef __attribute__((ext_vector_type(4))) float f32x4;

#define MFMA16(A,B,C) __builtin_amdgcn_mfma_f32_16x16x32_bf16(A,B,C,0,0,0)

static __device__ __forceinline__ unsigned short f2bf(float f) {
  unsigned u = __float_as_uint(f);
  u += 0x7fffu + ((u >> 16) & 1u);
  return (unsigned short)(u >> 16);
}
static __device__ __forceinline__ float bf2f(unsigned short h) {
  return __uint_as_float(((unsigned)h) << 16);
}

// ---------------------------------------------------------------------------
// Kernel 1: QKV projection (fp32 math), emit:
//   QHI/QLO/KHI/KLO : bf16 [B][NPIX][96]  (c-fast, cols 72..95 zero)
//   VG              : bf16 [B][80][NPIX]  (rows 72..79 zero)
// Stores for Q/K go through an LDS transpose so global writes are uint4
// coalesced (direct stores were 2B scatter at 192B lane stride).
// ---------------------------------------------------------------------------
#define QKS 104   // LDS row stride (ushorts); 208B = 16B-aligned rows

__global__ __launch_bounds__(256) void qkv_kernel(
    const float* __restrict__ x,
    const float* __restrict__ Wq, const float* __restrict__ bq,
    const float* __restrict__ Wk, const float* __restrict__ bk,
    const float* __restrict__ Wv, const float* __restrict__ bv,
    unsigned short* __restrict__ QHI, unsigned short* __restrict__ QLO,
    unsigned short* __restrict__ KHI, unsigned short* __restrict__ KLO,
    unsigned short* __restrict__ VG)
{
  __shared__ float xs[CIN * 32];
  __shared__ __align__(16) unsigned short qhs[32 * QKS];
  __shared__ __align__(16) unsigned short qls[32 * QKS];
  __shared__ __align__(16) unsigned short khs[32 * QKS];
  __shared__ __align__(16) unsigned short kls[32 * QKS];

  const int t  = threadIdx.x;
  const int b  = blockIdx.y;
  const int n0 = blockIdx.x * 32;
  const int nl = t & 31;
  const int dg = t >> 5;          // 0..7, each handles 9 output channels
  const int d0 = dg * 9;

  for (int e = t; e < CIN * 32; e += 256) {
    int c = e >> 5, j = e & 31;
    xs[e] = x[((size_t)b * CIN + c) * NPIX + n0 + j];
  }
  __syncthreads();

  float aq[9], ak[9], av[9];
#pragma unroll
  for (int dd = 0; dd < 9; ++dd) { aq[dd] = bq[d0+dd]; ak[dd] = bk[d0+dd]; av[dd] = bv[d0+dd]; }

  for (int c = 0; c < CIN; ++c) {
    float xv = xs[c * 32 + nl];
#pragma unroll
    for (int dd = 0; dd < 9; ++dd) {
      aq[dd] += Wq[(d0+dd) * CIN + c] * xv;
      ak[dd] += Wk[(d0+dd) * CIN + c] * xv;
      av[dd] += Wv[(d0+dd) * CIN + c] * xv;
    }
  }

  const int n = n0 + nl;
#pragma unroll
  for (int dd = 0; dd < 9; ++dd) {
    int d = d0 + dd;
    unsigned short qh = f2bf(aq[dd]);
    unsigned short ql = f2bf(aq[dd] - bf2f(qh));
    unsigned short kh = f2bf(ak[dd]);
    unsigned short kl = f2bf(ak[dd] - bf2f(kh));
    qhs[nl * QKS + d] = qh;  qls[nl * QKS + d] = ql;
    khs[nl * QKS + d] = kh;  kls[nl * QKS + d] = kl;
    VG[((size_t)b * 80 + d) * NPIX + n] = f2bf(av[dd]);   // n lane-fast: coalesced
  }
  if (t < 32) {
    for (int cp = 0; cp < 8; ++cp) VG[((size_t)b * 80 + 72 + cp) * NPIX + n0 + t] = 0;
  }
  __syncthreads();

  // coalesced uint4 stores: 32 rows x 12 uint4 per array (cols 9..11 = zero pad)
  const size_t ob = ((size_t)b * NPIX + n0) * CP;
  uint4 z; z.x = z.y = z.z = z.w = 0u;
  for (int f = t; f < 384; f += 256) {
    int row = f / 12, col = f % 12;
    size_t dst = ob + (size_t)row * CP + col * 8;
    *(uint4*)(QHI + dst) = (col < 9) ? *(const uint4*)(qhs + row * QKS + col * 8) : z;
    *(uint4*)(QLO + dst) = (col < 9) ? *(const uint4*)(qls + row * QKS + col * 8) : z;
    *(uint4*)(KHI + dst) = (col < 9) ? *(const uint4*)(khs + row * QKS + col * 8) : z;
    *(uint4*)(KLO + dst) = (col < 9) ? *(const uint4*)(kls + row * QKS + col * 8) : z;
  }
}

// ---------------------------------------------------------------------------
// Kernel 2: fused flash attention with split-j.
// 1D grid of 1152 blocks; xcd = bid&7 (HW round-robin) picks the split, so
// each XCD's L2 holds exactly its own K/V chunk (~626 KB) -> L2-served
// re-reads instead of L3 thrash.
// 4 waves/block, each wave 32 rows (2 m-tiles). BJ=64 per iteration.
// LDS: K tiles aliased with P tiles and the fp32 epilogue transpose buffer.
// Scores in split-bf16 (qhi*khi + qlo*khi + qhi*klo), fp32 accum.
// Output: OPART fp32 [S*B][72][NPIX] c-major unnormalized,
//         MLPART float2 [S*B][NPIX]
// ---------------------------------------------------------------------------
#define KSP 104   // LDS row stride for k tiles (ushorts)
#define VSP 72    // LDS row stride for v tile
#define PSP 72    // LDS row stride for p tile

__global__ __launch_bounds__(256, 3) void flash_kernel(
    const unsigned short* __restrict__ QHI, const unsigned short* __restrict__ QLO,
    const unsigned short* __restrict__ KHI, const unsigned short* __restrict__ KLO,
    const unsigned short* __restrict__ VG,
    float* __restrict__ OPART, float2* __restrict__ MLPART)
{
  // K tiles (live: stage->scores) aliased with P tiles (live: softmax->PV)
  // and with the per-wave fp32 epilogue transpose slots (live: after K-loop).
  __shared__ __align__(16) union {
    struct { unsigned short kh[64 * KSP]; unsigned short kl[64 * KSP]; } k;   // 26,624 B
    unsigned short ps[4][32 * PSP];                                           // 18,432 B
    float eb[4][1664];                                                        // 26,624 B
  } u;
  __shared__ __align__(16) unsigned short ls_vs[80 * VSP];

  const int t    = threadIdx.x;
  const int w    = t >> 6;
  const int lane = t & 63;
  const int quad = lane >> 4;
  const int l15  = lane & 15;

  const int bid  = blockIdx.x;
  const int sp   = bid & 7;          // split == XCD id (round-robin dispatch)
  const int slot = bid >> 3;         // 0..143
  const int b    = slot / 72;
  const int it   = slot % 72;
  const int i0w  = it * 128 + w * 32;

  // Q fragments in registers for the whole block (A-operand layout:
  // m = lane&15, k = quad*8 + j  -> 16B contiguous in [row][c] storage)
  bf16x8 qh[2][3], ql[2][3];
#pragma unroll
  for (int mi = 0; mi < 2; ++mi)
#pragma unroll
    for (int ks = 0; ks < 3; ++ks) {
      size_t off = ((size_t)b * NPIX + i0w + mi * 16 + l15) * CP + ks * 32 + quad * 8;
      qh[mi][ks] = *(const bf16x8*)(QHI + off);
      ql[mi][ks] = *(const bf16x8*)(QLO + off);
    }

  f32x4 oacc[2][5];
#pragma unroll
  for (int mi = 0; mi < 2; ++mi)
#pragma unroll
    for (int nt = 0; nt < 5; ++nt) oacc[mi][nt] = (f32x4){0.f, 0.f, 0.f, 0.f};
  float m_run[2][4], l_run[2][4];
#pragma unroll
  for (int mi = 0; mi < 2; ++mi)
#pragma unroll
    for (int r = 0; r < 4; ++r) { m_run[mi][r] = -1e30f; l_run[mi][r] = 0.f; }

  for (int jt = 0; jt < JTILES; ++jt) {
    const int j0 = sp * JCHUNK + jt * 64;
    // ---- stage K(hi,lo) and V tiles into LDS ----
    {
      const unsigned short* kh = KHI + ((size_t)b * NPIX + j0) * CP;
      const unsigned short* kl = KLO + ((size_t)b * NPIX + j0) * CP;
      for (int idx = t; idx < 768; idx += 256) {
        int r = idx / 12, c = idx % 12;
        *(uint4*)(u.k.kh + r * KSP + c * 8) = *(const uint4*)(kh + r * CP + c * 8);
        *(uint4*)(u.k.kl + r * KSP + c * 8) = *(const uint4*)(kl + r * CP + c * 8);
      }
      for (int idx = t; idx < 640; idx += 256) {
        int r = idx >> 3, c = idx & 7;
        *(uint4*)(ls_vs + r * VSP + c * 8) =
            *(const uint4*)(VG + ((size_t)b * 80 + r) * NPIX + j0 + c * 8);
      }
    }
    __syncthreads();

    // ---- scores: S = Qhi*Khi + Qlo*Khi + Qhi*Klo ----
    f32x4 sacc[2][4];
#pragma unroll
    for (int mi = 0; mi < 2; ++mi)
#pragma unroll
      for (int ni = 0; ni < 4; ++ni) sacc[mi][ni] = (f32x4){0.f, 0.f, 0.f, 0.f};

#pragma unroll
    for (int ni = 0; ni < 4; ++ni) {
      const unsigned short* krh = u.k.kh + (ni * 16 + l15) * KSP;
      const unsigned short* krl = u.k.kl + (ni * 16 + l15) * KSP;
#pragma unroll
      for (int ks = 0; ks < 3; ++ks) {
        bf16x8 fkh = *(const bf16x8*)(krh + ks * 32 + quad * 8);
        bf16x8 fkl = *(const bf16x8*)(krl + ks * 32 + quad * 8);
#pragma unroll
        for (int mi = 0; mi < 2; ++mi) {
          sacc[mi][ni] = MFMA16(qh[mi][ks], fkh, sacc[mi][ni]);
          sacc[mi][ni] = MFMA16(ql[mi][ks], fkh, sacc[mi][ni]);
          sacc[mi][ni] = MFMA16(qh[mi][ks], fkl, sacc[mi][ni]);
        }
      }
    }
    __syncthreads();   // K tiles dead after this -> P may overwrite them

    // ---- online softmax (wave-local; D layout: col=lane&15, row=quad*4+reg) ----
    unsigned short* psw = u.ps[w];
#pragma unroll
    for (int mi = 0; mi < 2; ++mi) {
      float al[4];
#pragma unroll
      for (int r = 0; r < 4; ++r) {
        float tm = fmaxf(fmaxf(sacc[mi][0][r], sacc[mi][1][r]),
                         fmaxf(sacc[mi][2][r], sacc[mi][3][r]));
        tm = fmaxf(tm, __shfl_xor(tm, 1));
        tm = fmaxf(tm, __shfl_xor(tm, 2));
        tm = fmaxf(tm, __shfl_xor(tm, 4));
        tm = fmaxf(tm, __shfl_xor(tm, 8));
        float mold = m_run[mi][r];
        float mnew = fmaxf(mold, tm);
        float alpha = __expf(mold - mnew);
        float rs = 0.f;
#pragma unroll
        for (int ni = 0; ni < 4; ++ni) {
          float pv = __expf(sacc[mi][ni][r] - mnew);
          sacc[mi][ni][r] = pv;
          rs += pv;
        }
        rs += __shfl_xor(rs, 1);
        rs += __shfl_xor(rs, 2);
        rs += __shfl_xor(rs, 4);
        rs += __shfl_xor(rs, 8);
        m_run[mi][r] = mnew;
        l_run[mi][r] = l_run[mi][r] * alpha + rs;
        al[r] = alpha;
      }
#pragma unroll
      for (int nt = 0; nt < 5; ++nt)
#pragma unroll
        for (int r = 0; r < 4; ++r) oacc[mi][nt][r] *= al[r];
      // write P (bf16) to LDS in [row][j] layout for the A-operand of PV
#pragma unroll
      for (int ni = 0; ni < 4; ++ni)
#pragma unroll
        for (int r = 0; r < 4; ++r) {
          int row = mi * 16 + quad * 4 + r;
          int col = ni * 16 + l15;
          psw[row * PSP + col] = f2bf(sacc[mi][ni][r]);
        }
    }

    // ---- PV: O[i][c] += P[i][j] * V[c][j]  (own-wave P + shared read-only V) ----
#pragma unroll
    for (int js = 0; js < 2; ++js) {
      bf16x8 pf[2];
#pragma unroll
      for (int mi = 0; mi < 2; ++mi)
        pf[mi] = *(const bf16x8*)(psw + (mi * 16 + l15) * PSP + js * 32 + quad * 8);
#pragma unroll
      for (int nt = 0; nt < 5; ++nt) {
        bf16x8 vf = *(const bf16x8*)(ls_vs + (nt * 16 + l15) * VSP + js * 32 + quad * 8);
#pragma unroll
        for (int mi = 0; mi < 2; ++mi)
          oacc[mi][nt] = MFMA16(pf[mi], vf, oacc[mi][nt]);
      }
    }
    __syncthreads();   // all PV reads done before next stage overwrites
  }

  // ---- epilogue: transpose O tile through LDS, store c-major coalesced ----
  const size_t sb = (size_t)(sp * 2 + b);
  float* slotp = u.eb[w];              // wave-private 1664-float slot (16x73 used)
#pragma unroll
  for (int mi = 0; mi < 2; ++mi) {
    __syncthreads();                   // prior LDS use (P reads / prev reads) done
#pragma unroll
    for (int nt = 0; nt < 5; ++nt)
#pragma unroll
      for (int r = 0; r < 4; ++r) {
        int row = quad * 4 + r;        // n within 16-row tile
        int col = nt * 16 + l15;       // channel
        if (col < 72) slotp[row * 73 + col] = oacc[mi][nt][r];
      }
    __syncthreads();
#pragma unroll
    for (int cc = 0; cc < 18; ++cc) {
      int c = cc * 4 + quad;
      OPART[(sb * 72 + c) * NPIX + i0w + mi * 16 + l15] = slotp[l15 * 73 + c];
    }
#pragma unroll
    for (int r = 0; r < 4; ++r)
      if (l15 == 0)
        MLPART[sb * NPIX + i0w + mi * 16 + quad * 4 + r] =
            make_float2(m_run[mi][r], l_run[mi][r]);
  }
}

// ---------------------------------------------------------------------------
// Kernel 3: combine splits + factor-4 pooling, fused. All reads coalesced
// (OPART is c-major: lane-consecutive n).
// ---------------------------------------------------------------------------
__global__ __launch_bounds__(256) void combine_pool_kernel(
    const float* __restrict__ x, const float* __restrict__ OPART,
    const float2* __restrict__ MLPART, float* __restrict__ out)
{
  int id = blockIdx.x * 256 + threadIdx.x;
  if (id >= 2 * 18 * NPIX) return;
  int n = id % NPIX;
  int rest = id / NPIX;
  int g = rest % 18, b = rest / 18;

  float2 ml[SPLITS];
  float M = -1e30f;
#pragma unroll
  for (int s = 0; s < SPLITS; ++s) {
    ml[s] = MLPART[((size_t)(s * 2 + b)) * NPIX + n];
    M = fmaxf(M, ml[s].x);
  }
  float L = 0.f;
  float4 acc = make_float4(0.f, 0.f, 0.f, 0.f);
#pragma unroll
  for (int s = 0; s < SPLITS; ++s) {
    float e = __expf(ml[s].x - M);
    L += ml[s].y * e;
    size_t base = (((size_t)(s * 2 + b)) * 72 + g * 4) * NPIX + n;
    acc.x += OPART[base] * e;
    acc.y += OPART[base + NPIX] * e;
    acc.z += OPART[base + 2 * NPIX] * e;
    acc.w += OPART[base + 3 * NPIX] * e;
  }
  float inv = 1.0f / L;
  const float* xp = x + ((size_t)b * CIN + g * 4) * NPIX + n;
  out[id] = (xp[0] * acc.x + xp[NPIX] * acc.y +
             xp[2 * NPIX] * acc.z + xp[3 * NPIX] * acc.w) * inv;
}

// ---------------------------------------------------------------------------
extern "C" void kernel_launch(void* const* d_in, const int* in_sizes, int n_in,
                              void* d_out, int out_size, void* d_ws, size_t ws_size,
                              hipStream_t stream) {
  const float* x  = (const float*)d_in[0];
  const float* Wq = (const float*)d_in[1];
  const float* bq = (const float*)d_in[2];
  const float* Wk = (const float*)d_in[3];
  const float* bk = (const float*)d_in[4];
  const float* Wv = (const float*)d_in[5];
  const float* bv = (const float*)d_in[6];
  float* out = (float*)d_out;

  char* p = (char*)d_ws;
  const size_t szQK = (size_t)2 * NPIX * CP * 2;     // 3,538,944 B each
  unsigned short* QHI = (unsigned short*)p; p += szQK;
  unsigned short* QLO = (unsigned short*)p; p += szQK;
  unsigned short* KHI = (unsigned short*)p; p += szQK;
  unsigned short* KLO = (unsigned short*)p; p += szQK;
  unsigned short* VG  = (unsigned short*)p; p += (size_t)2 * 80 * NPIX * 2;
  float* OPART = (float*)p; p += (size_t)SPLITS * 2 * 72 * NPIX * 4;  // 42.5 MB
  float2* MLPART = (float2*)p; p += (size_t)SPLITS * 2 * NPIX * 8;    // 1.2 MB
  // total ws use ~61 MB

  qkv_kernel<<<dim3(NPIX / 32, 2), 256, 0, stream>>>(x, Wq, bq, Wk, bk, Wv, bv,
                                                     QHI, QLO, KHI, KLO, VG);
  flash_kernel<<<dim3(1152), 256, 0, stream>>>(QHI, QLO, KHI, KLO, VG, OPART, MLPART);
  combine_pool_kernel<<<(2 * 18 * NPIX + 255) / 256, 256, 0, stream>>>(x, OPART, MLPART, out);
}

// Round 4
// 257.595 us; speedup vs baseline: 3.6798x; 1.3196x over previous
//
#include <hip/hip_runtime.h>

#define NPIX 9216
#define CIN 72
#define CP 96
#define SPLITS 8
#define JCHUNK (NPIX / SPLITS)   // 1152
#define JTILES (JCHUNK / 64)     // 18
#define FIXM 32.0f               // fixed softmax shift; safe to s<120 (14 sigma)

typedef __attribute__((ext_vector_type(8))) short bf16x8;
typedef __attribute__((ext_vector_type(8))) _Float16 f16x8;
typedef __attribute__((ext_vector_type(4))) float f32x4;

#define MFMA_BF16(A,B,C) __builtin_amdgcn_mfma_f32_16x16x32_bf16(A,B,C,0,0,0)
#define MFMA_F16(A,B,C)  __builtin_amdgcn_mfma_f32_16x16x32_f16(A,B,C,0,0,0)

static __device__ __forceinline__ unsigned short f2bf(float f) {
  unsigned u = __float_as_uint(f);
  u += 0x7fffu + ((u >> 16) & 1u);
  return (unsigned short)(u >> 16);
}
static __device__ __forceinline__ unsigned short f2h(float f) {
  _Float16 h = (_Float16)f;            // v_cvt_f16_f32, RTN-even
  return *(unsigned short*)&h;
}

// ---------------------------------------------------------------------------
// Kernel 1: QKV projection (fp32 math), emit:
//   QH/KH : fp16 bits [B][NPIX][96]  (c-fast, cols 72..95 zero)
//   VG    : bf16 [B][80][NPIX]       (rows 72..79 zero)
// Q/K stores go through an LDS transpose -> coalesced uint4 global writes.
// ---------------------------------------------------------------------------
#define QKS 104   // LDS row stride (ushorts); 208B, 16B-aligned rows

__global__ __launch_bounds__(256) void qkv_kernel(
    const float* __restrict__ x,
    const float* __restrict__ Wq, const float* __restrict__ bq,
    const float* __restrict__ Wk, const float* __restrict__ bk,
    const float* __restrict__ Wv, const float* __restrict__ bv,
    unsigned short* __restrict__ QH, unsigned short* __restrict__ KH,
    unsigned short* __restrict__ VG)
{
  __shared__ float xs[CIN * 32];
  __shared__ __align__(16) unsigned short qhs[32 * QKS];
  __shared__ __align__(16) unsigned short khs[32 * QKS];

  const int t  = threadIdx.x;
  const int b  = blockIdx.y;
  const int n0 = blockIdx.x * 32;
  const int nl = t & 31;
  const int dg = t >> 5;          // 0..7, each handles 9 output channels
  const int d0 = dg * 9;

  for (int e = t; e < CIN * 32; e += 256) {
    int c = e >> 5, j = e & 31;
    xs[e] = x[((size_t)b * CIN + c) * NPIX + n0 + j];
  }
  __syncthreads();

  float aq[9], ak[9], av[9];
#pragma unroll
  for (int dd = 0; dd < 9; ++dd) { aq[dd] = bq[d0+dd]; ak[dd] = bk[d0+dd]; av[dd] = bv[d0+dd]; }

  for (int c = 0; c < CIN; ++c) {
    float xv = xs[c * 32 + nl];
#pragma unroll
    for (int dd = 0; dd < 9; ++dd) {
      aq[dd] += Wq[(d0+dd) * CIN + c] * xv;
      ak[dd] += Wk[(d0+dd) * CIN + c] * xv;
      av[dd] += Wv[(d0+dd) * CIN + c] * xv;
    }
  }

  const int n = n0 + nl;
#pragma unroll
  for (int dd = 0; dd < 9; ++dd) {
    int d = d0 + dd;
    qhs[nl * QKS + d] = f2h(aq[dd]);
    khs[nl * QKS + d] = f2h(ak[dd]);
    VG[((size_t)b * 80 + d) * NPIX + n] = f2bf(av[dd]);   // n lane-fast: coalesced
  }
  if (t < 32) {
    for (int cp = 0; cp < 8; ++cp) VG[((size_t)b * 80 + 72 + cp) * NPIX + n0 + t] = 0;
  }
  __syncthreads();

  // coalesced uint4 stores: 32 rows x 12 uint4 per array (cols 9..11 = zero pad)
  const size_t ob = ((size_t)b * NPIX + n0) * CP;
  uint4 z; z.x = z.y = z.z = z.w = 0u;
  for (int f = t; f < 384; f += 256) {
    int row = f / 12, col = f % 12;
    size_t dst = ob + (size_t)row * CP + col * 8;
    *(uint4*)(QH + dst) = (col < 9) ? *(const uint4*)(qhs + row * QKS + col * 8) : z;
    *(uint4*)(KH + dst) = (col < 9) ? *(const uint4*)(khs + row * QKS + col * 8) : z;
  }
}

// ---------------------------------------------------------------------------
// Kernel 2: fused flash attention, split-j, fixed softmax max.
// 1D grid of 1152 blocks; xcd = bid&7 picks the split -> per-XCD L2-resident
// K/V chunk. 4 waves/block, 32 rows/wave, BJ=64.
// Scores: single fp16 MFMA. p = exp(s - FIXM); no per-tile max/sum reduce,
// no alpha rescale; per-lane l partials reduced once in epilogue.
// Output: OPART fp32 [S*B][72][NPIX] c-major (shared scale), LPART [S*B][NPIX]
// ---------------------------------------------------------------------------
#define KSP 104   // k tile stride (ushorts)
#define VSP 72    // v tile stride
#define PSP 72    // p tile stride

__global__ __launch_bounds__(256, 4) void flash_kernel(
    const unsigned short* __restrict__ QH, const unsigned short* __restrict__ KH,
    const unsigned short* __restrict__ VG,
    float* __restrict__ OPART, float* __restrict__ LPART)
{
  // K tile (live: stage->scores) aliased with P tiles (softmax->PV) and the
  // fp32 epilogue transpose slots (after K-loop).
  __shared__ __align__(16) union {
    unsigned short kh[64 * KSP];     // 13,312 B
    unsigned short ps[4][32 * PSP];  // 18,432 B
    float eb[4][16 * 73];            // 18,688 B
  } u;
  __shared__ __align__(16) unsigned short ls_vs[80 * VSP];  // 11,520 B

  const int t    = threadIdx.x;
  const int w    = t >> 6;
  const int lane = t & 63;
  const int quad = lane >> 4;
  const int l15  = lane & 15;

  const int bid  = blockIdx.x;
  const int sp   = bid & 7;          // split == XCD id (round-robin dispatch)
  const int slot = bid >> 3;         // 0..143
  const int b    = slot / 72;
  const int it   = slot % 72;
  const int i0w  = it * 128 + w * 32;

  // Q fragments in registers for the whole block (A-layout: m=lane&15,
  // k=quad*8+j -> contiguous 16B in [row][c] storage)
  f16x8 qh[2][3];
#pragma unroll
  for (int mi = 0; mi < 2; ++mi)
#pragma unroll
    for (int ks = 0; ks < 3; ++ks) {
      size_t off = ((size_t)b * NPIX + i0w + mi * 16 + l15) * CP + ks * 32 + quad * 8;
      qh[mi][ks] = *(const f16x8*)(QH + off);
    }

  f32x4 oacc[2][5];
#pragma unroll
  for (int mi = 0; mi < 2; ++mi)
#pragma unroll
    for (int nt = 0; nt < 5; ++nt) oacc[mi][nt] = (f32x4){0.f, 0.f, 0.f, 0.f};
  float lsum[2][4];
#pragma unroll
  for (int mi = 0; mi < 2; ++mi)
#pragma unroll
    for (int r = 0; r < 4; ++r) lsum[mi][r] = 0.f;

  for (int jt = 0; jt < JTILES; ++jt) {
    const int j0 = sp * JCHUNK + jt * 64;
    // ---- stage K and V tiles into LDS ----
    {
      const unsigned short* kh = KH + ((size_t)b * NPIX + j0) * CP;
      for (int idx = t; idx < 768; idx += 256) {
        int r = idx / 12, c = idx % 12;
        *(uint4*)(u.kh + r * KSP + c * 8) = *(const uint4*)(kh + r * CP + c * 8);
      }
      for (int idx = t; idx < 640; idx += 256) {
        int r = idx >> 3, c = idx & 7;
        *(uint4*)(ls_vs + r * VSP + c * 8) =
            *(const uint4*)(VG + ((size_t)b * 80 + r) * NPIX + j0 + c * 8);
      }
    }
    __syncthreads();

    // ---- scores: single fp16 MFMA ----
    f32x4 sacc[2][4];
#pragma unroll
    for (int mi = 0; mi < 2; ++mi)
#pragma unroll
      for (int ni = 0; ni < 4; ++ni) sacc[mi][ni] = (f32x4){0.f, 0.f, 0.f, 0.f};

#pragma unroll
    for (int ni = 0; ni < 4; ++ni) {
      const unsigned short* krh = u.kh + (ni * 16 + l15) * KSP;
#pragma unroll
      for (int ks = 0; ks < 3; ++ks) {
        f16x8 fkh = *(const f16x8*)(krh + ks * 32 + quad * 8);
        sacc[0][ni] = MFMA_F16(qh[0][ks], fkh, sacc[0][ni]);
        sacc[1][ni] = MFMA_F16(qh[1][ks], fkh, sacc[1][ni]);
      }
    }
    __syncthreads();   // K tile dead -> P may overwrite it

    // ---- fixed-max softmax: p = exp(s - FIXM), per-lane l partials ----
    unsigned short* psw = u.ps[w];
#pragma unroll
    for (int mi = 0; mi < 2; ++mi)
#pragma unroll
      for (int ni = 0; ni < 4; ++ni)
#pragma unroll
        for (int r = 0; r < 4; ++r) {
          float p = __expf(sacc[mi][ni][r] - FIXM);
          lsum[mi][r] += p;
          psw[(mi * 16 + quad * 4 + r) * PSP + ni * 16 + l15] = f2bf(p);
        }

    // ---- PV: O[i][c] += P[i][j] * V[c][j] (own-wave P, shared V) ----
#pragma unroll
    for (int js = 0; js < 2; ++js) {
      bf16x8 pf[2];
#pragma unroll
      for (int mi = 0; mi < 2; ++mi)
        pf[mi] = *(const bf16x8*)(psw + (mi * 16 + l15) * PSP + js * 32 + quad * 8);
#pragma unroll
      for (int nt = 0; nt < 5; ++nt) {
        bf16x8 vf = *(const bf16x8*)(ls_vs + (nt * 16 + l15) * VSP + js * 32 + quad * 8);
#pragma unroll
        for (int mi = 0; mi < 2; ++mi)
          oacc[mi][nt] = MFMA_BF16(pf[mi], vf, oacc[mi][nt]);
      }
    }
    __syncthreads();   // all PV reads done before next stage overwrites
  }

  // ---- epilogue: reduce l across lanes, transpose O via LDS, store c-major ----
  const size_t sb = (size_t)(sp * 2 + b);
#pragma unroll
  for (int mi = 0; mi < 2; ++mi)
#pragma unroll
    for (int r = 0; r < 4; ++r) {
      float v = lsum[mi][r];
      v += __shfl_xor(v, 1);
      v += __shfl_xor(v, 2);
      v += __shfl_xor(v, 4);
      v += __shfl_xor(v, 8);
      if (l15 == 0)
        LPART[sb * NPIX + i0w + mi * 16 + quad * 4 + r] = v;
    }

  float* slotp = u.eb[w];              // wave-private 16x73 fp32 slot
#pragma unroll
  for (int mi = 0; mi < 2; ++mi) {
    __syncthreads();                   // prior LDS use done
#pragma unroll
    for (int nt = 0; nt < 5; ++nt)
#pragma unroll
      for (int r = 0; r < 4; ++r) {
        int row = quad * 4 + r;        // n within 16-row tile
        int col = nt * 16 + l15;       // channel
        if (col < 72) slotp[row * 73 + col] = oacc[mi][nt][r];
      }
    __syncthreads();
#pragma unroll
    for (int cc = 0; cc < 18; ++cc) {
      int c = cc * 4 + quad;
      OPART[(sb * 72 + c) * NPIX + i0w + mi * 16 + l15] = slotp[l15 * 73 + c];
    }
  }
}

// ---------------------------------------------------------------------------
// Kernel 3: combine splits (shared scale -> plain sums) + factor-4 pooling.
// ---------------------------------------------------------------------------
__global__ __launch_bounds__(256) void combine_pool_kernel(
    const float* __restrict__ x, const float* __restrict__ OPART,
    const float* __restrict__ LPART, float* __restrict__ out)
{
  int id = blockIdx.x * 256 + threadIdx.x;
  if (id >= 2 * 18 * NPIX) return;
  int n = id % NPIX;
  int rest = id / NPIX;
  int g = rest % 18, b = rest / 18;

  float L = 0.f;
  float4 acc = make_float4(0.f, 0.f, 0.f, 0.f);
#pragma unroll
  for (int s = 0; s < SPLITS; ++s) {
    size_t sb = (size_t)(s * 2 + b);
    L += LPART[sb * NPIX + n];
    size_t base = (sb * 72 + g * 4) * NPIX + n;
    acc.x += OPART[base];
    acc.y += OPART[base + NPIX];
    acc.z += OPART[base + 2 * NPIX];
    acc.w += OPART[base + 3 * NPIX];
  }
  float inv = 1.0f / L;
  const float* xp = x + ((size_t)b * CIN + g * 4) * NPIX + n;
  out[id] = (xp[0] * acc.x + xp[NPIX] * acc.y +
             xp[2 * NPIX] * acc.z + xp[3 * NPIX] * acc.w) * inv;
}

// ---------------------------------------------------------------------------
extern "C" void kernel_launch(void* const* d_in, const int* in_sizes, int n_in,
                              void* d_out, int out_size, void* d_ws, size_t ws_size,
                              hipStream_t stream) {
  const float* x  = (const float*)d_in[0];
  const float* Wq = (const float*)d_in[1];
  const float* bq = (const float*)d_in[2];
  const float* Wk = (const float*)d_in[3];
  const float* bk = (const float*)d_in[4];
  const float* Wv = (const float*)d_in[5];
  const float* bv = (const float*)d_in[6];
  float* out = (float*)d_out;

  char* p = (char*)d_ws;
  const size_t szQK = (size_t)2 * NPIX * CP * 2;     // 3,538,944 B each
  unsigned short* QH = (unsigned short*)p; p += szQK;
  unsigned short* KH = (unsigned short*)p; p += szQK;
  unsigned short* VG = (unsigned short*)p; p += (size_t)2 * 80 * NPIX * 2;
  float* OPART = (float*)p; p += (size_t)SPLITS * 2 * 72 * NPIX * 4;  // 42.5 MB
  float* LPART = (float*)p; p += (size_t)SPLITS * 2 * NPIX * 4;       // 0.6 MB
  // total ws use ~53 MB

  qkv_kernel<<<dim3(NPIX / 32, 2), 256, 0, stream>>>(x, Wq, bq, Wk, bk, Wv, bv,
                                                     QH, KH, VG);
  flash_kernel<<<dim3(1152), 256, 0, stream>>>(QH, KH, VG, OPART, LPART);
  combine_pool_kernel<<<(2 * 18 * NPIX + 255) / 256, 256, 0, stream>>>(x, OPART, LPART, out);
}

// Round 5
// 216.732 us; speedup vs baseline: 4.3736x; 1.1885x over previous
//
#include <hip/hip_runtime.h>

#define NPIX 9216
#define CIN 72
#define CP 96
#define SPLITS 8
#define JCHUNK (NPIX / SPLITS)   // 1152
#define JTILES (JCHUNK / 64)     // 18
#define FIXM 32.0f               // fixed softmax shift; safe to s<120 (14 sigma)

typedef __attribute__((ext_vector_type(8))) short bf16x8;
typedef __attribute__((ext_vector_type(8))) _Float16 f16x8;
typedef __attribute__((ext_vector_type(4))) float f32x4;

#define MFMA_BF16(A,B,C) __builtin_amdgcn_mfma_f32_16x16x32_bf16(A,B,C,0,0,0)
#define MFMA_F16(A,B,C)  __builtin_amdgcn_mfma_f32_16x16x32_f16(A,B,C,0,0,0)

static __device__ __forceinline__ unsigned short f2bf(float f) {
  unsigned u = __float_as_uint(f);
  u += 0x7fffu + ((u >> 16) & 1u);
  return (unsigned short)(u >> 16);
}
static __device__ __forceinline__ float bf2f(unsigned short h) {
  return __uint_as_float(((unsigned)h) << 16);
}
static __device__ __forceinline__ unsigned short f2h(float f) {
  _Float16 h = (_Float16)f;            // v_cvt_f16_f32, RTN-even
  return *(unsigned short*)&h;
}

// ---------------------------------------------------------------------------
// Kernel 0: W prep — split-bf16 (hi/lo) of Wq/Wk/Wv, padded to [80][96], zeros
// in pad rows/cols. WH/WL: [3][80][96] ushort.
// ---------------------------------------------------------------------------
__global__ __launch_bounds__(256) void wprep_kernel(
    const float* __restrict__ Wq, const float* __restrict__ Wk,
    const float* __restrict__ Wv,
    unsigned short* __restrict__ WH, unsigned short* __restrict__ WL)
{
  int id = blockIdx.x * 256 + threadIdx.x;
  if (id >= 3 * 80 * 96) return;
  int mat = id / (80 * 96);
  int rem = id % (80 * 96);
  int d = rem / 96, c = rem % 96;
  const float* W = (mat == 0) ? Wq : (mat == 1) ? Wk : Wv;
  float v = (d < 72 && c < 72) ? W[d * 72 + c] : 0.f;
  unsigned short hi = f2bf(v);
  WH[id] = hi;
  WL[id] = f2bf(v - bf2f(hi));
}

// ---------------------------------------------------------------------------
// Kernel 1: QKV projection as split-bf16 MFMA GEMM.
// Out[d][n] = sum_c W[d][c] X[c][n], computed hi*hi + hi*lo + lo*hi (fp32 acc,
// rel err ~1e-5 << fp16 rounding). Block = 64 px, 4 waves x 16 px each; all
// 80 (padded) channels x 3 mats per wave. X tile staged transposed [px][c]
// as bf16 hi/lo; Q/K outputs go via LDS transpose -> coalesced uint4 stores;
// V stored [c][n] direct.
// ---------------------------------------------------------------------------
#define XTS 104   // LDS row stride (ushorts), 208 B: 16B-aligned rows

__global__ __launch_bounds__(256, 4) void qkv_kernel(
    const float* __restrict__ x,
    const unsigned short* __restrict__ WH, const unsigned short* __restrict__ WL,
    const float* __restrict__ bq, const float* __restrict__ bk,
    const float* __restrict__ bv,
    unsigned short* __restrict__ QH, unsigned short* __restrict__ KH,
    unsigned short* __restrict__ VG)
{
  __shared__ __align__(16) unsigned short xth[64 * XTS];
  __shared__ __align__(16) unsigned short xtl[64 * XTS];
  __shared__ __align__(16) unsigned short obuf[64 * XTS];

  const int t    = threadIdx.x;
  const int w    = t >> 6;
  const int lane = t & 63;
  const int quad = lane >> 4;
  const int l15  = lane & 15;
  const int bid  = blockIdx.x;
  const int b    = bid / 144;
  const int n0   = (bid % 144) * 64;

  // stage X tile, split-bf16, transposed to [px][c] (c-pad zeroed)
  for (int e = t; e < 72 * 64; e += 256) {
    int c = e >> 6, px = e & 63;
    float f = x[((size_t)b * CIN + c) * NPIX + n0 + px];
    unsigned short hi = f2bf(f);
    xth[px * XTS + c] = hi;
    xtl[px * XTS + c] = f2bf(f - bf2f(hi));
  }
  for (int e = t; e < 24 * 64; e += 256) {
    int c = 72 + (e >> 6), px = e & 63;
    xth[px * XTS + c] = 0;
    xtl[px * XTS + c] = 0;
  }
  __syncthreads();

  // B-operand fragments (n = l15 = px, k = quad*8+j), held for whole kernel
  bf16x8 xbh[3], xbl[3];
#pragma unroll
  for (int ks = 0; ks < 3; ++ks) {
    int off = (w * 16 + l15) * XTS + ks * 32 + quad * 8;
    xbh[ks] = *(const bf16x8*)(xth + off);
    xbl[ks] = *(const bf16x8*)(xtl + off);
  }

  for (int mat = 0; mat < 3; ++mat) {
    const unsigned short* wh = WH + mat * 80 * 96;
    const unsigned short* wl = WL + mat * 80 * 96;
    const float* bias = (mat == 0) ? bq : (mat == 1) ? bk : bv;

    f32x4 acc[5];
#pragma unroll
    for (int dm = 0; dm < 5; ++dm) {
      acc[dm] = (f32x4){0.f, 0.f, 0.f, 0.f};
#pragma unroll
      for (int ks = 0; ks < 3; ++ks) {
        // A-operand: m = l15 = d, k = quad*8+j; contiguous 16B in [d][c]
        bf16x8 ah = *(const bf16x8*)(wh + (dm * 16 + l15) * 96 + ks * 32 + quad * 8);
        bf16x8 al = *(const bf16x8*)(wl + (dm * 16 + l15) * 96 + ks * 32 + quad * 8);
        acc[dm] = MFMA_BF16(ah, xbh[ks], acc[dm]);
        acc[dm] = MFMA_BF16(ah, xbl[ks], acc[dm]);
        acc[dm] = MFMA_BF16(al, xbh[ks], acc[dm]);
      }
    }

    if (mat < 2) {
      // Q/K: bias + fp16, transpose via obuf, coalesced uint4 store
      __syncthreads();                 // obuf free (previous store done)
#pragma unroll
      for (int dm = 0; dm < 5; ++dm)
#pragma unroll
        for (int r = 0; r < 4; ++r) {
          int d = dm * 16 + quad * 4 + r;
          float v = acc[dm][r] + (d < 72 ? bias[d] : 0.f);
          obuf[(w * 16 + l15) * XTS + d] = f2h(v);
        }
      __syncthreads();
      unsigned short* outp = (mat == 0) ? QH : KH;
      const size_t ob = ((size_t)b * NPIX + n0) * CP;
      uint4 z; z.x = z.y = z.z = z.w = 0u;
      for (int f = t; f < 768; f += 256) {
        int row = f / 12, col = f % 12;
        *(uint4*)(outp + ob + (size_t)row * CP + col * 8) =
            (col < 10) ? *(const uint4*)(obuf + row * XTS + col * 8) : z;
      }
    } else {
      // V: bias + bf16, store [c][n] direct (pad rows d=72..79 store zero)
#pragma unroll
      for (int dm = 0; dm < 5; ++dm)
#pragma unroll
        for (int r = 0; r < 4; ++r) {
          int d = dm * 16 + quad * 4 + r;
          float v = acc[dm][r] + (d < 72 ? bias[d] : 0.f);
          VG[((size_t)b * 80 + d) * NPIX + n0 + w * 16 + l15] = f2bf(v);
        }
    }
  }
}

// ---------------------------------------------------------------------------
// Kernel 2: fused flash attention, split-j, fixed softmax max.
// Grid 768 (1D); sp = bid&7 -> per-XCD L2-resident K/V chunk.
// Block = 192 rows; 4 waves x 48 rows (3 m-tiles) each -> K/V LDS tiles
// amortized over 1.5x more rows per read than round 4. BJ=64.
// Output: OPART fp32 [S*B][72][NPIX] c-major (shared scale), LPART [S*B][NPIX]
// ---------------------------------------------------------------------------
#define KSP 104   // k tile stride (ushorts)
#define VSP 72    // v tile stride
#define PSP 72    // p tile stride

__global__ __launch_bounds__(256, 3) void flash_kernel(
    const unsigned short* __restrict__ QH, const unsigned short* __restrict__ KH,
    const unsigned short* __restrict__ VG,
    float* __restrict__ OPART, float* __restrict__ LPART)
{
  // K tile (stage->scores) aliased with P tiles (softmax->PV) and the fp32
  // epilogue transpose slots (after K-loop).
  __shared__ __align__(16) union {
    unsigned short kh[64 * KSP];     // 13,312 B
    unsigned short ps[4][48 * PSP];  // 27,648 B
    float eb[4][16 * 73];            // 18,688 B
  } u;
  __shared__ __align__(16) unsigned short ls_vs[80 * VSP];  // 11,520 B

  const int t    = threadIdx.x;
  const int w    = t >> 6;
  const int lane = t & 63;
  const int quad = lane >> 4;
  const int l15  = lane & 15;

  const int bid  = blockIdx.x;
  const int sp   = bid & 7;          // split == XCD id (round-robin dispatch)
  const int slot = bid >> 3;         // 0..95
  const int b    = slot / 48;
  const int it   = slot % 48;
  const int i0w  = it * 192 + w * 48;

  // Q fragments in registers for the whole block
  f16x8 qh[3][3];
#pragma unroll
  for (int mi = 0; mi < 3; ++mi)
#pragma unroll
    for (int ks = 0; ks < 3; ++ks) {
      size_t off = ((size_t)b * NPIX + i0w + mi * 16 + l15) * CP + ks * 32 + quad * 8;
      qh[mi][ks] = *(const f16x8*)(QH + off);
    }

  f32x4 oacc[3][5];
#pragma unroll
  for (int mi = 0; mi < 3; ++mi)
#pragma unroll
    for (int nt = 0; nt < 5; ++nt) oacc[mi][nt] = (f32x4){0.f, 0.f, 0.f, 0.f};
  float lsum[3][4];
#pragma unroll
  for (int mi = 0; mi < 3; ++mi)
#pragma unroll
    for (int r = 0; r < 4; ++r) lsum[mi][r] = 0.f;

  for (int jt = 0; jt < JTILES; ++jt) {
    const int j0 = sp * JCHUNK + jt * 64;
    // ---- stage K and V tiles into LDS ----
    {
      const unsigned short* kh = KH + ((size_t)b * NPIX + j0) * CP;
      for (int idx = t; idx < 768; idx += 256) {
        int r = idx / 12, c = idx % 12;
        *(uint4*)(u.kh + r * KSP + c * 8) = *(const uint4*)(kh + r * CP + c * 8);
      }
      for (int idx = t; idx < 640; idx += 256) {
        int r = idx >> 3, c = idx & 7;
        *(uint4*)(ls_vs + r * VSP + c * 8) =
            *(const uint4*)(VG + ((size_t)b * 80 + r) * NPIX + j0 + c * 8);
      }
    }
    __syncthreads();

    // ---- scores: fp16 MFMA; fkh transient, sacc[3][4] live ----
    f32x4 sacc[3][4];
#pragma unroll
    for (int mi = 0; mi < 3; ++mi)
#pragma unroll
      for (int ni = 0; ni < 4; ++ni) sacc[mi][ni] = (f32x4){0.f, 0.f, 0.f, 0.f};

#pragma unroll
    for (int ks = 0; ks < 3; ++ks)
#pragma unroll
      for (int ni = 0; ni < 4; ++ni) {
        f16x8 fkh = *(const f16x8*)(u.kh + (ni * 16 + l15) * KSP + ks * 32 + quad * 8);
        sacc[0][ni] = MFMA_F16(qh[0][ks], fkh, sacc[0][ni]);
        sacc[1][ni] = MFMA_F16(qh[1][ks], fkh, sacc[1][ni]);
        sacc[2][ni] = MFMA_F16(qh[2][ks], fkh, sacc[2][ni]);
      }
    __syncthreads();   // K tile dead -> P may overwrite it

    // ---- fixed-max softmax: p = exp(s - FIXM), per-lane l partials ----
    unsigned short* psw = u.ps[w];
#pragma unroll
    for (int mi = 0; mi < 3; ++mi)
#pragma unroll
      for (int ni = 0; ni < 4; ++ni)
#pragma unroll
        for (int r = 0; r < 4; ++r) {
          float p = __expf(sacc[mi][ni][r] - FIXM);
          lsum[mi][r] += p;
          psw[(mi * 16 + quad * 4 + r) * PSP + ni * 16 + l15] = f2bf(p);
        }

    // ---- PV: O[i][c] += P[i][j] * V[c][j] (own-wave P, shared V) ----
#pragma unroll
    for (int js = 0; js < 2; ++js) {
      bf16x8 pf[3];
#pragma unroll
      for (int mi = 0; mi < 3; ++mi)
        pf[mi] = *(const bf16x8*)(psw + (mi * 16 + l15) * PSP + js * 32 + quad * 8);
#pragma unroll
      for (int nt = 0; nt < 5; ++nt) {
        bf16x8 vf = *(const bf16x8*)(ls_vs + (nt * 16 + l15) * VSP + js * 32 + quad * 8);
#pragma unroll
        for (int mi = 0; mi < 3; ++mi)
          oacc[mi][nt] = MFMA_BF16(pf[mi], vf, oacc[mi][nt]);
      }
    }
    __syncthreads();   // all PV reads done before next stage overwrites
  }

  // ---- epilogue: reduce l across lanes, transpose O via LDS, store c-major ----
  const size_t sb = (size_t)(sp * 2 + b);
#pragma unroll
  for (int mi = 0; mi < 3; ++mi)
#pragma unroll
    for (int r = 0; r < 4; ++r) {
      float v = lsum[mi][r];
      v += __shfl_xor(v, 1);
      v += __shfl_xor(v, 2);
      v += __shfl_xor(v, 4);
      v += __shfl_xor(v, 8);
      if (l15 == 0)
        LPART[sb * NPIX + i0w + mi * 16 + quad * 4 + r] = v;
    }

  float* slotp = u.eb[w];              // wave-private 16x73 fp32 slot
#pragma unroll
  for (int mi = 0; mi < 3; ++mi) {
    __syncthreads();                   // prior LDS use done
#pragma unroll
    for (int nt = 0; nt < 5; ++nt)
#pragma unroll
      for (int r = 0; r < 4; ++r) {
        int row = quad * 4 + r;        // n within 16-row tile
        int col = nt * 16 + l15;       // channel
        if (col < 72) slotp[row * 73 + col] = oacc[mi][nt][r];
      }
    __syncthreads();
#pragma unroll
    for (int cc = 0; cc < 18; ++cc) {
      int c = cc * 4 + quad;
      OPART[(sb * 72 + c) * NPIX + i0w + mi * 16 + l15] = slotp[l15 * 73 + c];
    }
  }
}

// ---------------------------------------------------------------------------
// Kernel 3: combine splits (shared scale -> plain sums) + factor-4 pooling.
// float4 over n: 4 pixels/thread, all loads/stores 16B coalesced.
// ---------------------------------------------------------------------------
__global__ __launch_bounds__(256) void combine_pool_kernel(
    const float* __restrict__ x, const float* __restrict__ OPART,
    const float* __restrict__ LPART, float* __restrict__ out)
{
  int id = blockIdx.x * 256 + threadIdx.x;
  if (id >= 2 * 18 * (NPIX / 4)) return;
  int n = (id % (NPIX / 4)) * 4;
  int rest = id / (NPIX / 4);
  int g = rest % 18, b = rest / 18;

  float4 L = make_float4(0.f, 0.f, 0.f, 0.f);
  float4 a0 = L, a1 = L, a2 = L, a3 = L;
#pragma unroll
  for (int s = 0; s < SPLITS; ++s) {
    size_t sb = (size_t)(s * 2 + b);
    float4 l4 = *(const float4*)(LPART + sb * NPIX + n);
    L.x += l4.x; L.y += l4.y; L.z += l4.z; L.w += l4.w;
    size_t base = (sb * 72 + g * 4) * NPIX + n;
    float4 o0 = *(const float4*)(OPART + base);
    float4 o1 = *(const float4*)(OPART + base + NPIX);
    float4 o2 = *(const float4*)(OPART + base + 2 * NPIX);
    float4 o3 = *(const float4*)(OPART + base + 3 * NPIX);
    a0.x += o0.x; a0.y += o0.y; a0.z += o0.z; a0.w += o0.w;
    a1.x += o1.x; a1.y += o1.y; a1.z += o1.z; a1.w += o1.w;
    a2.x += o2.x; a2.y += o2.y; a2.z += o2.z; a2.w += o2.w;
    a3.x += o3.x; a3.y += o3.y; a3.z += o3.z; a3.w += o3.w;
  }
  size_t xb = ((size_t)b * CIN + g * 4) * NPIX + n;
  float4 x0 = *(const float4*)(x + xb);
  float4 x1 = *(const float4*)(x + xb + NPIX);
  float4 x2 = *(const float4*)(x + xb + 2 * NPIX);
  float4 x3 = *(const float4*)(x + xb + 3 * NPIX);
  float4 r;
  r.x = (x0.x * a0.x + x1.x * a1.x + x2.x * a2.x + x3.x * a3.x) / L.x;
  r.y = (x0.y * a0.y + x1.y * a1.y + x2.y * a2.y + x3.y * a3.y) / L.y;
  r.z = (x0.z * a0.z + x1.z * a1.z + x2.z * a2.z + x3.z * a3.z) / L.z;
  r.w = (x0.w * a0.w + x1.w * a1.w + x2.w * a2.w + x3.w * a3.w) / L.w;
  *(float4*)(out + (size_t)id * 4) = r;
}

// ---------------------------------------------------------------------------
extern "C" void kernel_launch(void* const* d_in, const int* in_sizes, int n_in,
                              void* d_out, int out_size, void* d_ws, size_t ws_size,
                              hipStream_t stream) {
  const float* x  = (const float*)d_in[0];
  const float* Wq = (const float*)d_in[1];
  const float* bq = (const float*)d_in[2];
  const float* Wk = (const float*)d_in[3];
  const float* bk = (const float*)d_in[4];
  const float* Wv = (const float*)d_in[5];
  const float* bv = (const float*)d_in[6];
  float* out = (float*)d_out;

  char* p = (char*)d_ws;
  const size_t szQK = (size_t)2 * NPIX * CP * 2;     // 3,538,944 B each
  unsigned short* QH = (unsigned short*)p; p += szQK;
  unsigned short* KH = (unsigned short*)p; p += szQK;
  unsigned short* VG = (unsigned short*)p; p += (size_t)2 * 80 * NPIX * 2;
  unsigned short* WH = (unsigned short*)p; p += (size_t)3 * 80 * 96 * 2;
  unsigned short* WL = (unsigned short*)p; p += (size_t)3 * 80 * 96 * 2;
  float* OPART = (float*)p; p += (size_t)SPLITS * 2 * 72 * NPIX * 4;  // 42.5 MB
  float* LPART = (float*)p; p += (size_t)SPLITS * 2 * NPIX * 4;       // 0.6 MB
  // total ws use ~53 MB

  wprep_kernel<<<(3 * 80 * 96 + 255) / 256, 256, 0, stream>>>(Wq, Wk, Wv, WH, WL);
  qkv_kernel<<<288, 256, 0, stream>>>(x, WH, WL, bq, bk, bv, QH, KH, VG);
  flash_kernel<<<768, 256, 0, stream>>>(QH, KH, VG, OPART, LPART);
  combine_pool_kernel<<<(2 * 18 * (NPIX / 4) + 255) / 256, 256, 0, stream>>>(
      x, OPART, LPART, out);
}

// Round 6
// 185.968 us; speedup vs baseline: 5.0971x; 1.1654x over previous
//
#include <hip/hip_runtime.h>

#define NPIX 9216
#define CIN 72
#define CP 96
#define SPLITS 8
#define JCHUNK (NPIX / SPLITS)   // 1152
#define JTILES (JCHUNK / 64)     // 18
#define FIXM 32.0f               // fixed softmax shift; safe to s<120 (14 sigma)

typedef __attribute__((ext_vector_type(8))) short bf16x8;
typedef __attribute__((ext_vector_type(8))) _Float16 f16x8;
typedef __attribute__((ext_vector_type(4))) float f32x4;

#define MFMA_BF16(A,B,C) __builtin_amdgcn_mfma_f32_16x16x32_bf16(A,B,C,0,0,0)
#define MFMA_F16(A,B,C)  __builtin_amdgcn_mfma_f32_16x16x32_f16(A,B,C,0,0,0)

static __device__ __forceinline__ unsigned short f2bf(float f) {
  unsigned u = __float_as_uint(f);
  u += 0x7fffu + ((u >> 16) & 1u);
  return (unsigned short)(u >> 16);
}
static __device__ __forceinline__ float bf2f(unsigned short h) {
  return __uint_as_float(((unsigned)h) << 16);
}
static __device__ __forceinline__ unsigned short f2h(float f) {
  _Float16 h = (_Float16)f;            // v_cvt_f16_f32, RTN-even
  return *(unsigned short*)&h;
}

// ---------------------------------------------------------------------------
// Kernel 0: W prep — split-bf16 (hi/lo) of Wq/Wk/Wv, padded to [80][96].
// ---------------------------------------------------------------------------
__global__ __launch_bounds__(256) void wprep_kernel(
    const float* __restrict__ Wq, const float* __restrict__ Wk,
    const float* __restrict__ Wv,
    unsigned short* __restrict__ WH, unsigned short* __restrict__ WL)
{
  int id = blockIdx.x * 256 + threadIdx.x;
  if (id >= 3 * 80 * 96) return;
  int mat = id / (80 * 96);
  int rem = id % (80 * 96);
  int d = rem / 96, c = rem % 96;
  const float* W = (mat == 0) ? Wq : (mat == 1) ? Wk : Wv;
  float v = (d < 72 && c < 72) ? W[d * 72 + c] : 0.f;
  unsigned short hi = f2bf(v);
  WH[id] = hi;
  WL[id] = f2bf(v - bf2f(hi));
}

// ---------------------------------------------------------------------------
// Kernel 1: QKV projection as split-bf16 MFMA GEMM (hi*hi + hi*lo + lo*hi).
// Block = 64 px, 4 waves x 16 px; QH/KH via LDS transpose -> uint4 stores.
// ---------------------------------------------------------------------------
#define XTS 104   // LDS row stride (ushorts), 208 B: 16B-aligned rows

__global__ __launch_bounds__(256, 4) void qkv_kernel(
    const float* __restrict__ x,
    const unsigned short* __restrict__ WH, const unsigned short* __restrict__ WL,
    const float* __restrict__ bq, const float* __restrict__ bk,
    const float* __restrict__ bv,
    unsigned short* __restrict__ QH, unsigned short* __restrict__ KH,
    unsigned short* __restrict__ VG)
{
  __shared__ __align__(16) unsigned short xth[64 * XTS];
  __shared__ __align__(16) unsigned short xtl[64 * XTS];
  __shared__ __align__(16) unsigned short obuf[64 * XTS];

  const int t    = threadIdx.x;
  const int w    = t >> 6;
  const int lane = t & 63;
  const int quad = lane >> 4;
  const int l15  = lane & 15;
  const int bid  = blockIdx.x;
  const int b    = bid / 144;
  const int n0   = (bid % 144) * 64;

  // stage X tile, split-bf16, transposed to [px][c] (c-pad zeroed)
  for (int e = t; e < 72 * 64; e += 256) {
    int c = e >> 6, px = e & 63;
    float f = x[((size_t)b * CIN + c) * NPIX + n0 + px];
    unsigned short hi = f2bf(f);
    xth[px * XTS + c] = hi;
    xtl[px * XTS + c] = f2bf(f - bf2f(hi));
  }
  for (int e = t; e < 24 * 64; e += 256) {
    int c = 72 + (e >> 6), px = e & 63;
    xth[px * XTS + c] = 0;
    xtl[px * XTS + c] = 0;
  }
  __syncthreads();

  // B-operand fragments (n = l15 = px, k = quad*8+j), held for whole kernel
  bf16x8 xbh[3], xbl[3];
#pragma unroll
  for (int ks = 0; ks < 3; ++ks) {
    int off = (w * 16 + l15) * XTS + ks * 32 + quad * 8;
    xbh[ks] = *(const bf16x8*)(xth + off);
    xbl[ks] = *(const bf16x8*)(xtl + off);
  }

  for (int mat = 0; mat < 3; ++mat) {
    const unsigned short* wh = WH + mat * 80 * 96;
    const unsigned short* wl = WL + mat * 80 * 96;
    const float* bias = (mat == 0) ? bq : (mat == 1) ? bk : bv;

    f32x4 acc[5];
#pragma unroll
    for (int dm = 0; dm < 5; ++dm) {
      acc[dm] = (f32x4){0.f, 0.f, 0.f, 0.f};
#pragma unroll
      for (int ks = 0; ks < 3; ++ks) {
        bf16x8 ah = *(const bf16x8*)(wh + (dm * 16 + l15) * 96 + ks * 32 + quad * 8);
        bf16x8 al = *(const bf16x8*)(wl + (dm * 16 + l15) * 96 + ks * 32 + quad * 8);
        acc[dm] = MFMA_BF16(ah, xbh[ks], acc[dm]);
        acc[dm] = MFMA_BF16(ah, xbl[ks], acc[dm]);
        acc[dm] = MFMA_BF16(al, xbh[ks], acc[dm]);
      }
    }

    if (mat < 2) {
      __syncthreads();                 // obuf free (previous store done)
#pragma unroll
      for (int dm = 0; dm < 5; ++dm)
#pragma unroll
        for (int r = 0; r < 4; ++r) {
          int d = dm * 16 + quad * 4 + r;
          float v = acc[dm][r] + (d < 72 ? bias[d] : 0.f);
          obuf[(w * 16 + l15) * XTS + d] = f2h(v);
        }
      __syncthreads();
      unsigned short* outp = (mat == 0) ? QH : KH;
      const size_t ob = ((size_t)b * NPIX + n0) * CP;
      uint4 z; z.x = z.y = z.z = z.w = 0u;
      for (int f = t; f < 768; f += 256) {
        int row = f / 12, col = f % 12;
        *(uint4*)(outp + ob + (size_t)row * CP + col * 8) =
            (col < 10) ? *(const uint4*)(obuf + row * XTS + col * 8) : z;
      }
    } else {
#pragma unroll
      for (int dm = 0; dm < 5; ++dm)
#pragma unroll
        for (int r = 0; r < 4; ++r) {
          int d = dm * 16 + quad * 4 + r;
          float v = acc[dm][r] + (d < 72 ? bias[d] : 0.f);
          VG[((size_t)b * 80 + d) * NPIX + n0 + w * 16 + l15] = f2bf(v);
        }
    }
  }
}

// ---------------------------------------------------------------------------
// Kernel 2: fused flash attention, split-j, fixed softmax max.
// Grid 768; sp = bid&7 -> per-XCD L2-resident K/V chunk. 4 waves x 48 rows.
// Fused score->exp->P per 16x16 tile (no sacc array -> no spill); P-LDS is
// separate from K-LDS so no post-score barrier: 2 barriers/iter.
// PV reads own-wave P (lgkmcnt only, no barrier).
// ---------------------------------------------------------------------------
#define KSP 104   // k tile stride (ushorts)
#define VSP 72    // v tile stride
#define PSP 72    // p tile stride

__global__ __launch_bounds__(256, 3) void flash_kernel(
    const unsigned short* __restrict__ QH, const unsigned short* __restrict__ KH,
    const unsigned short* __restrict__ VG,
    float* __restrict__ OPART, float* __restrict__ LPART)
{
  __shared__ __align__(16) unsigned short ls_kh[64 * KSP];   // 13,312 B
  __shared__ __align__(16) unsigned short ls_vs[80 * VSP];   // 11,520 B
  __shared__ __align__(16) union {
    unsigned short ps[4][48 * PSP];  // 27,648 B (live: K-loop, per-wave slots)
    float eb[4][16 * 73];            // 18,688 B (live: epilogue only)
  } u;                               // total LDS 52,480 B -> 3 blocks/CU

  const int t    = threadIdx.x;
  const int w    = t >> 6;
  const int lane = t & 63;
  const int quad = lane >> 4;
  const int l15  = lane & 15;

  const int bid  = blockIdx.x;
  const int sp   = bid & 7;          // split == XCD id (round-robin dispatch)
  const int slot = bid >> 3;         // 0..95
  const int b    = slot / 48;
  const int it   = slot % 48;
  const int i0w  = it * 192 + w * 48;

  // Q fragments in registers for the whole block
  f16x8 qh[3][3];
#pragma unroll
  for (int mi = 0; mi < 3; ++mi)
#pragma unroll
    for (int ks = 0; ks < 3; ++ks) {
      size_t off = ((size_t)b * NPIX + i0w + mi * 16 + l15) * CP + ks * 32 + quad * 8;
      qh[mi][ks] = *(const f16x8*)(QH + off);
    }

  f32x4 oacc[3][5];
#pragma unroll
  for (int mi = 0; mi < 3; ++mi)
#pragma unroll
    for (int nt = 0; nt < 5; ++nt) oacc[mi][nt] = (f32x4){0.f, 0.f, 0.f, 0.f};
  float lsum[3][4];
#pragma unroll
  for (int mi = 0; mi < 3; ++mi)
#pragma unroll
    for (int r = 0; r < 4; ++r) lsum[mi][r] = 0.f;

  unsigned short* psw = u.ps[w];

  for (int jt = 0; jt < JTILES; ++jt) {
    const int j0 = sp * JCHUNK + jt * 64;
    // ---- stage K and V tiles into LDS ----
    {
      const unsigned short* kh = KH + ((size_t)b * NPIX + j0) * CP;
      for (int idx = t; idx < 768; idx += 256) {
        int r = idx / 12, c = idx % 12;
        *(uint4*)(ls_kh + r * KSP + c * 8) = *(const uint4*)(kh + r * CP + c * 8);
      }
      for (int idx = t; idx < 640; idx += 256) {
        int r = idx >> 3, c = idx & 7;
        *(uint4*)(ls_vs + r * VSP + c * 8) =
            *(const uint4*)(VG + ((size_t)b * 80 + r) * NPIX + j0 + c * 8);
      }
    }
    __syncthreads();

    // ---- fused scores -> exp -> P (per 16x16 tile; 4-reg transient acc) ----
#pragma unroll
    for (int ni = 0; ni < 4; ++ni) {
      f16x8 fkh[3];
#pragma unroll
      for (int ks = 0; ks < 3; ++ks)
        fkh[ks] = *(const f16x8*)(ls_kh + (ni * 16 + l15) * KSP + ks * 32 + quad * 8);
#pragma unroll
      for (int mi = 0; mi < 3; ++mi) {
        f32x4 s = (f32x4){0.f, 0.f, 0.f, 0.f};
        s = MFMA_F16(qh[mi][0], fkh[0], s);
        s = MFMA_F16(qh[mi][1], fkh[1], s);
        s = MFMA_F16(qh[mi][2], fkh[2], s);
#pragma unroll
        for (int r = 0; r < 4; ++r) {
          float p = __expf(s[r] - FIXM);
          lsum[mi][r] += p;
          psw[(mi * 16 + quad * 4 + r) * PSP + ni * 16 + l15] = f2bf(p);
        }
      }
    }

    // ---- PV: own-wave P (no barrier needed) + shared read-only V ----
#pragma unroll
    for (int js = 0; js < 2; ++js) {
      bf16x8 pf[3];
#pragma unroll
      for (int mi = 0; mi < 3; ++mi)
        pf[mi] = *(const bf16x8*)(psw + (mi * 16 + l15) * PSP + js * 32 + quad * 8);
#pragma unroll
      for (int nt = 0; nt < 5; ++nt) {
        bf16x8 vf = *(const bf16x8*)(ls_vs + (nt * 16 + l15) * VSP + js * 32 + quad * 8);
#pragma unroll
        for (int mi = 0; mi < 3; ++mi)
          oacc[mi][nt] = MFMA_BF16(pf[mi], vf, oacc[mi][nt]);
      }
    }
    __syncthreads();   // all waves done reading K/V before next staging
  }

  // ---- epilogue: reduce l across lanes, transpose O via LDS, store c-major ----
  const size_t sb = (size_t)(sp * 2 + b);
#pragma unroll
  for (int mi = 0; mi < 3; ++mi)
#pragma unroll
    for (int r = 0; r < 4; ++r) {
      float v = lsum[mi][r];
      v += __shfl_xor(v, 1);
      v += __shfl_xor(v, 2);
      v += __shfl_xor(v, 4);
      v += __shfl_xor(v, 8);
      if (l15 == 0)
        LPART[sb * NPIX + i0w + mi * 16 + quad * 4 + r] = v;
    }

  float* slotp = u.eb[w];              // wave-private 16x73 fp32 slot
#pragma unroll
  for (int mi = 0; mi < 3; ++mi) {
    __syncthreads();                   // prior LDS use done
#pragma unroll
    for (int nt = 0; nt < 5; ++nt)
#pragma unroll
      for (int r = 0; r < 4; ++r) {
        int row = quad * 4 + r;        // n within 16-row tile
        int col = nt * 16 + l15;       // channel
        if (col < 72) slotp[row * 73 + col] = oacc[mi][nt][r];
      }
    __syncthreads();
#pragma unroll
    for (int cc = 0; cc < 18; ++cc) {
      int c = cc * 4 + quad;
      OPART[(sb * 72 + c) * NPIX + i0w + mi * 16 + l15] = slotp[l15 * 73 + c];
    }
  }
}

// ---------------------------------------------------------------------------
// Kernel 3: combine splits (shared scale -> plain sums) + factor-4 pooling.
// ---------------------------------------------------------------------------
__global__ __launch_bounds__(256) void combine_pool_kernel(
    const float* __restrict__ x, const float* __restrict__ OPART,
    const float* __restrict__ LPART, float* __restrict__ out)
{
  int id = blockIdx.x * 256 + threadIdx.x;
  if (id >= 2 * 18 * (NPIX / 4)) return;
  int n = (id % (NPIX / 4)) * 4;
  int rest = id / (NPIX / 4);
  int g = rest % 18, b = rest / 18;

  float4 L = make_float4(0.f, 0.f, 0.f, 0.f);
  float4 a0 = L, a1 = L, a2 = L, a3 = L;
#pragma unroll
  for (int s = 0; s < SPLITS; ++s) {
    size_t sb = (size_t)(s * 2 + b);
    float4 l4 = *(const float4*)(LPART + sb * NPIX + n);
    L.x += l4.x; L.y += l4.y; L.z += l4.z; L.w += l4.w;
    size_t base = (sb * 72 + g * 4) * NPIX + n;
    float4 o0 = *(const float4*)(OPART + base);
    float4 o1 = *(const float4*)(OPART + base + NPIX);
    float4 o2 = *(const float4*)(OPART + base + 2 * NPIX);
    float4 o3 = *(const float4*)(OPART + base + 3 * NPIX);
    a0.x += o0.x; a0.y += o0.y; a0.z += o0.z; a0.w += o0.w;
    a1.x += o1.x; a1.y += o1.y; a1.z += o1.z; a1.w += o1.w;
    a2.x += o2.x; a2.y += o2.y; a2.z += o2.z; a2.w += o2.w;
    a3.x += o3.x; a3.y += o3.y; a3.z += o3.z; a3.w += o3.w;
  }
  size_t xb = ((size_t)b * CIN + g * 4) * NPIX + n;
  float4 x0 = *(const float4*)(x + xb);
  float4 x1 = *(const float4*)(x + xb + NPIX);
  float4 x2 = *(const float4*)(x + xb + 2 * NPIX);
  float4 x3 = *(const float4*)(x + xb + 3 * NPIX);
  float4 r;
  r.x = (x0.x * a0.x + x1.x * a1.x + x2.x * a2.x + x3.x * a3.x) / L.x;
  r.y = (x0.y * a0.y + x1.y * a1.y + x2.y * a2.y + x3.y * a3.y) / L.y;
  r.z = (x0.z * a0.z + x1.z * a1.z + x2.z * a2.z + x3.z * a3.z) / L.z;
  r.w = (x0.w * a0.w + x1.w * a1.w + x2.w * a2.w + x3.w * a3.w) / L.w;
  *(float4*)(out + (size_t)id * 4) = r;
}

// ---------------------------------------------------------------------------
extern "C" void kernel_launch(void* const* d_in, const int* in_sizes, int n_in,
                              void* d_out, int out_size, void* d_ws, size_t ws_size,
                              hipStream_t stream) {
  const float* x  = (const float*)d_in[0];
  const float* Wq = (const float*)d_in[1];
  const float* bq = (const float*)d_in[2];
  const float* Wk = (const float*)d_in[3];
  const float* bk = (const float*)d_in[4];
  const float* Wv = (const float*)d_in[5];
  const float* bv = (const float*)d_in[6];
  float* out = (float*)d_out;

  char* p = (char*)d_ws;
  const size_t szQK = (size_t)2 * NPIX * CP * 2;     // 3,538,944 B each
  unsigned short* QH = (unsigned short*)p; p += szQK;
  unsigned short* KH = (unsigned short*)p; p += szQK;
  unsigned short* VG = (unsigned short*)p; p += (size_t)2 * 80 * NPIX * 2;
  unsigned short* WH = (unsigned short*)p; p += (size_t)3 * 80 * 96 * 2;
  unsigned short* WL = (unsigned short*)p; p += (size_t)3 * 80 * 96 * 2;
  float* OPART = (float*)p; p += (size_t)SPLITS * 2 * 72 * NPIX * 4;  // 42.5 MB
  float* LPART = (float*)p; p += (size_t)SPLITS * 2 * NPIX * 4;       // 0.6 MB
  // total ws use ~53 MB

  wprep_kernel<<<(3 * 80 * 96 + 255) / 256, 256, 0, stream>>>(Wq, Wk, Wv, WH, WL);
  qkv_kernel<<<288, 256, 0, stream>>>(x, WH, WL, bq, bk, bv, QH, KH, VG);
  flash_kernel<<<768, 256, 0, stream>>>(QH, KH, VG, OPART, LPART);
  combine_pool_kernel<<<(2 * 18 * (NPIX / 4) + 255) / 256, 256, 0, stream>>>(
      x, OPART, LPART, out);
}

// Round 7
// 179.688 us; speedup vs baseline: 5.2752x; 1.0349x over previous
//
#include <hip/hip_runtime.h>

#define NPIX 9216
#define CIN 72
#define CP 96
#define SPLITS 8
#define JCHUNK (NPIX / SPLITS)   // 1152
#define JTILES (JCHUNK / 64)     // 18
// p = exp2(s*log2e - 32*log2e)  (fixed softmax shift 32; safe to s<120)
#define L2E   1.44269504088896f
#define EXPB  46.1662413084468f

typedef __attribute__((ext_vector_type(8))) short bf16x8;
typedef __attribute__((ext_vector_type(8))) _Float16 f16x8;
typedef __attribute__((ext_vector_type(4))) float f32x4;

#define MFMA_BF16(A,B,C) __builtin_amdgcn_mfma_f32_16x16x32_bf16(A,B,C,0,0,0)
#define MFMA_F16(A,B,C)  __builtin_amdgcn_mfma_f32_16x16x32_f16(A,B,C,0,0,0)

static __device__ __forceinline__ unsigned short f2bf(float f) {
  unsigned u = __float_as_uint(f);
  u += 0x7fffu + ((u >> 16) & 1u);
  return (unsigned short)(u >> 16);
}
static __device__ __forceinline__ float bf2f(unsigned short h) {
  return __uint_as_float(((unsigned)h) << 16);
}
static __device__ __forceinline__ unsigned short f2h(float f) {
  _Float16 h = (_Float16)f;
  return *(unsigned short*)&h;
}
// pack trunc-bf16 of (lo,hi) into one dword: [lo.hi16 | hi.hi16]
static __device__ __forceinline__ unsigned pack_bf_trunc(float lo, float hi) {
  return (__float_as_uint(lo) >> 16) | (__float_as_uint(hi) & 0xffff0000u);
}

// ---------------------------------------------------------------------------
// Kernel 0: W prep — split-bf16 (hi/lo) of Wq/Wk/Wv, padded to [80][96].
// ---------------------------------------------------------------------------
__global__ __launch_bounds__(256) void wprep_kernel(
    const float* __restrict__ Wq, const float* __restrict__ Wk,
    const float* __restrict__ Wv,
    unsigned short* __restrict__ WH, unsigned short* __restrict__ WL)
{
  int id = blockIdx.x * 256 + threadIdx.x;
  if (id >= 3 * 80 * 96) return;
  int mat = id / (80 * 96);
  int rem = id % (80 * 96);
  int d = rem / 96, c = rem % 96;
  const float* W = (mat == 0) ? Wq : (mat == 1) ? Wk : Wv;
  float v = (d < 72 && c < 72) ? W[d * 72 + c] : 0.f;
  unsigned short hi = f2bf(v);
  WH[id] = hi;
  WL[id] = f2bf(v - bf2f(hi));
}

// ---------------------------------------------------------------------------
// Kernel 1: QKV projection, split-bf16 MFMA GEMM, ONE WAVE per block (16 px)
// -> grid 1152 (was 288: occupancy-starved). Same 135 MFMA/wave.
// ---------------------------------------------------------------------------
#define XTS 104   // LDS row stride (ushorts), 208 B

__global__ __launch_bounds__(64) void qkv_kernel(
    const float* __restrict__ x,
    const unsigned short* __restrict__ WH, const unsigned short* __restrict__ WL,
    const float* __restrict__ bq, const float* __restrict__ bk,
    const float* __restrict__ bv,
    unsigned short* __restrict__ QH, unsigned short* __restrict__ KH,
    unsigned short* __restrict__ VG)
{
  __shared__ __align__(16) unsigned short xth[16 * XTS];
  __shared__ __align__(16) unsigned short xtl[16 * XTS];
  __shared__ __align__(16) unsigned short obuf[16 * XTS];

  const int t    = threadIdx.x;
  const int quad = t >> 4;
  const int l15  = t & 15;
  const int bid  = blockIdx.x;
  const int b    = bid / 576;
  const int n0   = (bid % 576) * 16;

  // stage X strip, split-bf16, transposed to [px][c]
  for (int e = t; e < 72 * 16; e += 64) {
    int c = e >> 4, px = e & 15;
    float f = x[((size_t)b * CIN + c) * NPIX + n0 + px];
    unsigned short hi = f2bf(f);
    xth[px * XTS + c] = hi;
    xtl[px * XTS + c] = f2bf(f - bf2f(hi));
  }
  for (int e = t; e < 24 * 16; e += 64) {
    int c = 72 + (e >> 4), px = e & 15;
    xth[px * XTS + c] = 0;
    xtl[px * XTS + c] = 0;
  }
  __syncthreads();

  bf16x8 xbh[3], xbl[3];
#pragma unroll
  for (int ks = 0; ks < 3; ++ks) {
    int off = l15 * XTS + ks * 32 + quad * 8;
    xbh[ks] = *(const bf16x8*)(xth + off);
    xbl[ks] = *(const bf16x8*)(xtl + off);
  }

  for (int mat = 0; mat < 3; ++mat) {
    const unsigned short* wh = WH + mat * 80 * 96;
    const unsigned short* wl = WL + mat * 80 * 96;
    const float* bias = (mat == 0) ? bq : (mat == 1) ? bk : bv;

    f32x4 acc[5];
#pragma unroll
    for (int dm = 0; dm < 5; ++dm) {
      acc[dm] = (f32x4){0.f, 0.f, 0.f, 0.f};
#pragma unroll
      for (int ks = 0; ks < 3; ++ks) {
        bf16x8 ah = *(const bf16x8*)(wh + (dm * 16 + l15) * 96 + ks * 32 + quad * 8);
        bf16x8 al = *(const bf16x8*)(wl + (dm * 16 + l15) * 96 + ks * 32 + quad * 8);
        acc[dm] = MFMA_BF16(ah, xbh[ks], acc[dm]);
        acc[dm] = MFMA_BF16(ah, xbl[ks], acc[dm]);
        acc[dm] = MFMA_BF16(al, xbh[ks], acc[dm]);
      }
    }

    if (mat < 2) {
      __syncthreads();                 // obuf free
#pragma unroll
      for (int dm = 0; dm < 5; ++dm)
#pragma unroll
        for (int r = 0; r < 4; ++r) {
          int d = dm * 16 + quad * 4 + r;
          float v = acc[dm][r] + (d < 72 ? bias[d] : 0.f);
          obuf[l15 * XTS + d] = f2h(v);
        }
      __syncthreads();
      unsigned short* outp = (mat == 0) ? QH : KH;
      const size_t ob = ((size_t)b * NPIX + n0) * CP;
      uint4 z; z.x = z.y = z.z = z.w = 0u;
      for (int f = t; f < 192; f += 64) {
        int row = f / 12, col = f % 12;
        *(uint4*)(outp + ob + (size_t)row * CP + col * 8) =
            (col < 10) ? *(const uint4*)(obuf + row * XTS + col * 8) : z;
      }
    } else {
#pragma unroll
      for (int dm = 0; dm < 5; ++dm)
#pragma unroll
        for (int r = 0; r < 4; ++r) {
          int d = dm * 16 + quad * 4 + r;
          float v = acc[dm][r] + (d < 72 ? bias[d] : 0.f);
          VG[((size_t)b * 80 + d) * NPIX + n0 + l15] = f2bf(v);
        }
    }
  }
}

// ---------------------------------------------------------------------------
// Kernel 2: fused flash attention, split-j, fixed softmax max, S^T scores.
// Scores computed TRANSPOSED (A=K, B=Q -> D[j][i]): each lane's 4 values are
// 4 consecutive j for one i -> exp + trunc-pack -> ONE ds_write_b64 per tile
// (was 4x conflicted ds_write_b16). PV side unchanged ([i][j] P layout).
// Grid 768; sp = bid&7 -> per-XCD L2-resident K/V chunk. 4 waves x 48 rows.
// Output: OPH bf16 [S*B][72][NPIX] c-major, LPART fp32 [S*B][NPIX].
// ---------------------------------------------------------------------------
#define KSP 104   // k tile stride (ushorts)
#define VSP 72    // v tile stride
#define PSP 72    // p tile stride (b64 writes 4-phase-optimal, b128 reads 8-phase)

__global__ __launch_bounds__(256, 3) void flash_kernel(
    const unsigned short* __restrict__ QH, const unsigned short* __restrict__ KH,
    const unsigned short* __restrict__ VG,
    unsigned short* __restrict__ OPH, float* __restrict__ LPART)
{
  __shared__ __align__(16) unsigned short ls_kh[64 * KSP];   // 13,312 B
  __shared__ __align__(16) unsigned short ls_vs[80 * VSP];   // 11,520 B
  __shared__ __align__(16) union {
    unsigned short ps[4][48 * PSP];  // 27,648 B (K-loop, per-wave slots)
    float eb[4][16 * 73];            // 18,688 B (epilogue only)
  } u;                               // total 52,480 B -> 3 blocks/CU

  const int t    = threadIdx.x;
  const int w    = t >> 6;
  const int lane = t & 63;
  const int quad = lane >> 4;
  const int l15  = lane & 15;

  const int bid  = blockIdx.x;
  const int sp   = bid & 7;
  const int slot = bid >> 3;
  const int b    = slot / 48;
  const int it   = slot % 48;
  const int i0w  = it * 192 + w * 48;

  // Q fragments (B-operand of S^T scores: n=l15=i, k=quad*8+c)
  f16x8 qh[3][3];
#pragma unroll
  for (int mi = 0; mi < 3; ++mi)
#pragma unroll
    for (int ks = 0; ks < 3; ++ks) {
      size_t off = ((size_t)b * NPIX + i0w + mi * 16 + l15) * CP + ks * 32 + quad * 8;
      qh[mi][ks] = *(const f16x8*)(QH + off);
    }

  f32x4 oacc[3][5];
#pragma unroll
  for (int mi = 0; mi < 3; ++mi)
#pragma unroll
    for (int nt = 0; nt < 5; ++nt) oacc[mi][nt] = (f32x4){0.f, 0.f, 0.f, 0.f};
  float lsum[3] = {0.f, 0.f, 0.f};   // all of a lane's p share i = mi*16+l15

  unsigned short* psw = u.ps[w];

  for (int jt = 0; jt < JTILES; ++jt) {
    const int j0 = sp * JCHUNK + jt * 64;
    // ---- stage K and V tiles into LDS ----
    {
      const unsigned short* kh = KH + ((size_t)b * NPIX + j0) * CP;
      for (int idx = t; idx < 768; idx += 256) {
        int r = idx / 12, c = idx % 12;
        *(uint4*)(ls_kh + r * KSP + c * 8) = *(const uint4*)(kh + r * CP + c * 8);
      }
      for (int idx = t; idx < 640; idx += 256) {
        int r = idx >> 3, c = idx & 7;
        *(uint4*)(ls_vs + r * VSP + c * 8) =
            *(const uint4*)(VG + ((size_t)b * 80 + r) * NPIX + j0 + c * 8);
      }
    }
    __syncthreads();

    // ---- S^T scores -> exp -> packed b64 P write ----
#pragma unroll
    for (int tj = 0; tj < 4; ++tj) {
      f16x8 fkh[3];
#pragma unroll
      for (int ks = 0; ks < 3; ++ks)
        fkh[ks] = *(const f16x8*)(ls_kh + (tj * 16 + l15) * KSP + ks * 32 + quad * 8);
#pragma unroll
      for (int mi = 0; mi < 3; ++mi) {
        f32x4 s = (f32x4){0.f, 0.f, 0.f, 0.f};
        s = MFMA_F16(fkh[0], qh[mi][0], s);   // A=K (m=j), B=Q (n=i)
        s = MFMA_F16(fkh[1], qh[mi][1], s);
        s = MFMA_F16(fkh[2], qh[mi][2], s);
        float p0 = __builtin_amdgcn_exp2f(__builtin_fmaf(s[0], L2E, -EXPB));
        float p1 = __builtin_amdgcn_exp2f(__builtin_fmaf(s[1], L2E, -EXPB));
        float p2 = __builtin_amdgcn_exp2f(__builtin_fmaf(s[2], L2E, -EXPB));
        float p3 = __builtin_amdgcn_exp2f(__builtin_fmaf(s[3], L2E, -EXPB));
        lsum[mi] += (p0 + p1) + (p2 + p3);
        uint2 pk;
        pk.x = pack_bf_trunc(p0, p1);
        pk.y = pack_bf_trunc(p2, p3);
        *(uint2*)(psw + (mi * 16 + l15) * PSP + tj * 16 + quad * 4) = pk;
      }
    }

    // ---- PV: own-wave P (lgkmcnt only) + shared read-only V ----
#pragma unroll
    for (int js = 0; js < 2; ++js) {
      bf16x8 pf[3];
#pragma unroll
      for (int mi = 0; mi < 3; ++mi)
        pf[mi] = *(const bf16x8*)(psw + (mi * 16 + l15) * PSP + js * 32 + quad * 8);
#pragma unroll
      for (int nt = 0; nt < 5; ++nt) {
        bf16x8 vf = *(const bf16x8*)(ls_vs + (nt * 16 + l15) * VSP + js * 32 + quad * 8);
#pragma unroll
        for (int mi = 0; mi < 3; ++mi)
          oacc[mi][nt] = MFMA_BF16(pf[mi], vf, oacc[mi][nt]);
      }
    }
    __syncthreads();   // all K/V reads done before next staging
  }

  // ---- epilogue: reduce l across quads, transpose O via LDS, store bf16 ----
  const size_t sb = (size_t)(sp * 2 + b);
#pragma unroll
  for (int mi = 0; mi < 3; ++mi) {
    float v = lsum[mi];
    v += __shfl_xor(v, 16);
    v += __shfl_xor(v, 32);
    if (quad == 0)
      LPART[sb * NPIX + i0w + mi * 16 + l15] = v;
  }

  float* slotp = u.eb[w];
#pragma unroll
  for (int mi = 0; mi < 3; ++mi) {
    __syncthreads();
#pragma unroll
    for (int nt = 0; nt < 5; ++nt)
#pragma unroll
      for (int r = 0; r < 4; ++r) {
        int row = quad * 4 + r;        // n within 16-row tile
        int col = nt * 16 + l15;       // channel
        if (col < 72) slotp[row * 73 + col] = oacc[mi][nt][r];
      }
    __syncthreads();
#pragma unroll
    for (int cc = 0; cc < 18; ++cc) {
      int c = cc * 4 + quad;
      OPH[(sb * 72 + c) * NPIX + i0w + mi * 16 + l15] = f2bf(slotp[l15 * 73 + c]);
    }
  }
}

// ---------------------------------------------------------------------------
// Kernel 3: combine splits (shared scale -> plain sums) + factor-4 pooling.
// OPH is bf16 -> 22 MB read instead of 43.
// ---------------------------------------------------------------------------
__global__ __launch_bounds__(256) void combine_pool_kernel(
    const float* __restrict__ x, const unsigned short* __restrict__ OPH,
    const float* __restrict__ LPART, float* __restrict__ out)
{
  int id = blockIdx.x * 256 + threadIdx.x;
  if (id >= 2 * 18 * (NPIX / 4)) return;
  int n = (id % (NPIX / 4)) * 4;
  int rest = id / (NPIX / 4);
  int g = rest % 18, b = rest / 18;

  float4 L = make_float4(0.f, 0.f, 0.f, 0.f);
  float4 a0 = L, a1 = L, a2 = L, a3 = L;
#pragma unroll
  for (int s = 0; s < SPLITS; ++s) {
    size_t sb = (size_t)(s * 2 + b);
    float4 l4 = *(const float4*)(LPART + sb * NPIX + n);
    L.x += l4.x; L.y += l4.y; L.z += l4.z; L.w += l4.w;
    size_t base = (sb * 72 + g * 4) * NPIX + n;
    uint2 u0 = *(const uint2*)(OPH + base);
    uint2 u1 = *(const uint2*)(OPH + base + NPIX);
    uint2 u2 = *(const uint2*)(OPH + base + 2 * NPIX);
    uint2 u3 = *(const uint2*)(OPH + base + 3 * NPIX);
    a0.x += __uint_as_float(u0.x << 16); a0.y += __uint_as_float(u0.x & 0xffff0000u);
    a0.z += __uint_as_float(u0.y << 16); a0.w += __uint_as_float(u0.y & 0xffff0000u);
    a1.x += __uint_as_float(u1.x << 16); a1.y += __uint_as_float(u1.x & 0xffff0000u);
    a1.z += __uint_as_float(u1.y << 16); a1.w += __uint_as_float(u1.y & 0xffff0000u);
    a2.x += __uint_as_float(u2.x << 16); a2.y += __uint_as_float(u2.x & 0xffff0000u);
    a2.z += __uint_as_float(u2.y << 16); a2.w += __uint_as_float(u2.y & 0xffff0000u);
    a3.x += __uint_as_float(u3.x << 16); a3.y += __uint_as_float(u3.x & 0xffff0000u);
    a3.z += __uint_as_float(u3.y << 16); a3.w += __uint_as_float(u3.y & 0xffff0000u);
  }
  size_t xb = ((size_t)b * CIN + g * 4) * NPIX + n;
  float4 x0 = *(const float4*)(x + xb);
  float4 x1 = *(const float4*)(x + xb + NPIX);
  float4 x2 = *(const float4*)(x + xb + 2 * NPIX);
  float4 x3 = *(const float4*)(x + xb + 3 * NPIX);
  float4 r;
  r.x = (x0.x * a0.x + x1.x * a1.x + x2.x * a2.x + x3.x * a3.x) / L.x;
  r.y = (x0.y * a0.y + x1.y * a1.y + x2.y * a2.y + x3.y * a3.y) / L.y;
  r.z = (x0.z * a0.z + x1.z * a1.z + x2.z * a2.z + x3.z * a3.z) / L.z;
  r.w = (x0.w * a0.w + x1.w * a1.w + x2.w * a2.w + x3.w * a3.w) / L.w;
  *(float4*)(out + (size_t)id * 4) = r;
}

// ---------------------------------------------------------------------------
extern "C" void kernel_launch(void* const* d_in, const int* in_sizes, int n_in,
                              void* d_out, int out_size, void* d_ws, size_t ws_size,
                              hipStream_t stream) {
  const float* x  = (const float*)d_in[0];
  const float* Wq = (const float*)d_in[1];
  const float* bq = (const float*)d_in[2];
  const float* Wk = (const float*)d_in[3];
  const float* bk = (const float*)d_in[4];
  const float* Wv = (const float*)d_in[5];
  const float* bv = (const float*)d_in[6];
  float* out = (float*)d_out;

  char* p = (char*)d_ws;
  const size_t szQK = (size_t)2 * NPIX * CP * 2;
  unsigned short* QH = (unsigned short*)p; p += szQK;
  unsigned short* KH = (unsigned short*)p; p += szQK;
  unsigned short* VG = (unsigned short*)p; p += (size_t)2 * 80 * NPIX * 2;
  unsigned short* WH = (unsigned short*)p; p += (size_t)3 * 80 * 96 * 2;
  unsigned short* WL = (unsigned short*)p; p += (size_t)3 * 80 * 96 * 2;
  unsigned short* OPH = (unsigned short*)p; p += (size_t)SPLITS * 2 * 72 * NPIX * 2; // 21.2 MB
  float* LPART = (float*)p; p += (size_t)SPLITS * 2 * NPIX * 4;                      // 0.6 MB
  // total ws use ~32 MB

  wprep_kernel<<<(3 * 80 * 96 + 255) / 256, 256, 0, stream>>>(Wq, Wk, Wv, WH, WL);
  qkv_kernel<<<1152, 64, 0, stream>>>(x, WH, WL, bq, bk, bv, QH, KH, VG);
  flash_kernel<<<768, 256, 0, stream>>>(QH, KH, VG, OPH, LPART);
  combine_pool_kernel<<<(2 * 18 * (NPIX / 4) + 255) / 256, 256, 0, stream>>>(
      x, OPH, LPART, out);
}